// Round 12
// baseline (827.990 us; speedup 1.0000x reference)
//
#include <hip/hip_runtime.h>
#include <hip/hip_bf16.h>

// ---------------- constants ----------------
#define NN 50000
#define MM 400000
#define BB 1000
#define FF 39
#define EE 11
#define GG 200
#define PP 128

typedef __attribute__((ext_vector_type(8))) short bf16x8;
typedef __attribute__((ext_vector_type(4))) float f32x4;
struct us4 { unsigned short x, y, z, w; };

// ---------------- helpers ----------------
__device__ __forceinline__ float bf2f(unsigned short u) {
  return __uint_as_float(((unsigned int)u) << 16);
}
__device__ __forceinline__ unsigned short f2bf(float x) {
  union { __hip_bfloat16 b; unsigned short u; } v;
  v.b = __float2bfloat16(x);
  return v.u;
}
__device__ __forceinline__ float rcp_f(float x) { return __builtin_amdgcn_rcpf(x); }
__device__ __forceinline__ float leakyf(float x) { return x > 0.f ? x : 0.01f * x; }
__device__ __forceinline__ float elu_fast(float x)  { return x > 0.f ? x : __expf(x) - 1.f; }
__device__ __forceinline__ float sigm_fast(float x) { return rcp_f(1.f + __expf(-x)); }
__device__ __forceinline__ float tanh_fast(float x) { return 1.f - 2.f * rcp_f(1.f + __expf(2.f * x)); }
template <typename T> __device__ __forceinline__ float ldv(const T* p);
template <> __device__ __forceinline__ float ldv<float>(const float* p) { return *p; }
template <> __device__ __forceinline__ float ldv<unsigned short>(const unsigned short* p) { return bf2f(*p); }

// direct global A-fragment load: 8 consecutive elements (row layout)
template <typename T>
__device__ __forceinline__ bf16x8 afrag(const T* base, size_t off) {
  if constexpr (sizeof(T) == 2) {
    return *(const bf16x8*)(base + off);
  } else {
    float4 f0 = *(const float4*)(base + off);
    float4 f1 = *(const float4*)(base + off + 4);
    short t[8];
    t[0] = (short)f2bf(f0.x); t[1] = (short)f2bf(f0.y);
    t[2] = (short)f2bf(f0.z); t[3] = (short)f2bf(f0.w);
    t[4] = (short)f2bf(f1.x); t[5] = (short)f2bf(f1.y);
    t[6] = (short)f2bf(f1.z); t[7] = (short)f2bf(f1.w);
    return *(bf16x8*)t;
  }
}

// ---------------- runtime dtype detection ----------------
__global__ __launch_bounds__(256) void detect_dtype(const unsigned int* __restrict__ w,
                                                    int* __restrict__ flag) {
  __shared__ int cnt[256];
  int c = 0;
  for (int i = threadIdx.x; i < 2048; i += 256) {
    unsigned int e = (w[i] >> 8) & 0x7F;
    c += (e >= 60 && e <= 64) ? 1 : 0;
  }
  cnt[threadIdx.x] = c;
  __syncthreads();
  for (int s = 128; s; s >>= 1) {
    if (threadIdx.x < s) cnt[threadIdx.x] += cnt[threadIdx.x + s];
    __syncthreads();
  }
  if (threadIdx.x == 0) *flag = (cnt[0] >= 1024) ? 1 : 0;
}

// ---------------- batched conversion to f32 ----------------
struct CvtJob { const void* s; float* d; int n; int pad; };
struct CvtJobs32 { CvtJob j[32]; };

__global__ __launch_bounds__(256) void cvt_any(CvtJobs32 jobs, const int* __restrict__ flag) {
  CvtJob job = jobs.j[blockIdx.y];
  int isbf = *flag;
  if (isbf) {
    const unsigned short* s = (const unsigned short*)job.s;
    for (int i = blockIdx.x * 256 + threadIdx.x; i < job.n; i += gridDim.x * 256)
      job.d[i] = bf2f(s[i]);
  } else {
    const float* s = (const float*)job.s;
    for (int i = blockIdx.x * 256 + threadIdx.x; i < job.n; i += gridDim.x * 256)
      job.d[i] = s[i];
  }
}

// Xn -> bf16 padded [N][40]
__global__ __launch_bounds__(256) void cvt_xn(const void* __restrict__ src,
                                              unsigned short* __restrict__ dstb,
                                              const int* __restrict__ flag, int N) {
  int isbf = *flag;
  int total = N * 40;
  for (int i = blockIdx.x * 256 + threadIdx.x; i < total; i += gridDim.x * 256) {
    int n = i / 40, k = i - n * 40;
    unsigned short v = 0;
    if (k < FF) {
      if (isbf) v = ((const unsigned short*)src)[n * FF + k];
      else      v = f2bf(((const float*)src)[n * FF + k]);
    }
    dstb[i] = v;
  }
}

// ---------------- fragment-major weight pack ----------------
struct PJob { const float* s; unsigned short* d; int K; int Ns; int coff; int nkc; };
struct PJobs28 { PJob j[28]; };

__global__ __launch_bounds__(256) void pack_bf16(PJobs28 jobs) {
  PJob job = jobs.j[blockIdx.y];
  int per = job.nkc * 512;
  int total = 14 * per;
  for (int idx = blockIdx.x * 256 + threadIdx.x; idx < total; idx += gridDim.x * 256) {
    int ct = idx / per, r = idx - ct * per;
    int kc = r >> 9, e = r & 511;
    int lane = e >> 3, j = e & 7;
    int n = ct * 16 + (lane & 15);
    int k = kc * 32 + (lane >> 4) * 8 + j;
    job.d[idx] = (k < job.K && n < GG)
        ? f2bf(job.s[(size_t)k * job.Ns + job.coff + n]) : (unsigned short)0;
  }
}

// ---------------- CSR build ----------------
__global__ __launch_bounds__(256) void hist_kernel(const int* __restrict__ dst,
                                                   int* __restrict__ cnt, int M) {
  int e = blockIdx.x * 256 + threadIdx.x;
  if (e < M) atomicAdd(&cnt[dst[e]], 1);
}

#define SCHUNK 2048
__global__ __launch_bounds__(256) void scan1_kernel(const int* __restrict__ cnt,
                                                    int* __restrict__ incl,
                                                    int* __restrict__ bsum, int n) {
  __shared__ int lds[256];
  int b = blockIdx.x, tid = threadIdx.x;
  int base = b * SCHUNK + tid * 8;
  int v[8], s = 0;
#pragma unroll
  for (int j = 0; j < 8; ++j) { int i = base + j; v[j] = (i < n) ? cnt[i] : 0; s += v[j]; }
  lds[tid] = s;
  __syncthreads();
  for (int o = 1; o < 256; o <<= 1) {
    int t = (tid >= o) ? lds[tid - o] : 0;
    __syncthreads();
    lds[tid] += t;
    __syncthreads();
  }
  int run = lds[tid] - s;
#pragma unroll
  for (int j = 0; j < 8; ++j) {
    run += v[j];
    int i = base + j;
    if (i < n) incl[i] = run;
  }
  if (tid == 255) bsum[b] = lds[255];
}

__global__ void scan2_kernel(int* __restrict__ bsum, int nb) {
  if (threadIdx.x == 0 && blockIdx.x == 0) {
    int run = 0;
    for (int i = 0; i < nb; ++i) { int t = bsum[i]; bsum[i] = run; run += t; }
  }
}

__global__ __launch_bounds__(256) void scan3_kernel(const int* __restrict__ incl,
                                                    const int* __restrict__ cnt,
                                                    const int* __restrict__ bsum,
                                                    int* __restrict__ offA,
                                                    int* __restrict__ cur, int n) {
  int i = blockIdx.x * 256 + threadIdx.x;
  if (i >= n) return;
  int o = incl[i] - cnt[i] + bsum[i / SCHUNK];
  offA[i] = o;
  cur[i] = o;
}

__global__ __launch_bounds__(256) void fill_kernel(const int* __restrict__ dst,
                                                   int* __restrict__ cur,
                                                   int* __restrict__ elist, int M) {
  int e = blockIdx.x * 256 + threadIdx.x;
  if (e >= M) return;
  int pos = atomicAdd(&cur[dst[e]], 1);
  elist[pos] = e;
}

// ---------------- layer-1 fused aggregation: 2 nodes per 128-thr block ----------------
__global__ __launch_bounds__(128) void l1_agg(
    const float* __restrict__ Xe, const unsigned short* __restrict__ xa,
    const unsigned short* __restrict__ hvnew,
    const float* __restrict__ pe1w_e, const float* __restrict__ pe1b,
    const float* __restrict__ pe2w_n, const float* __restrict__ pe2w_e,
    const float* __restrict__ pe2b, const int* __restrict__ srcA,
    const int* __restrict__ offA, const int* __restrict__ cntA, const int* __restrict__ elist,
    unsigned short* __restrict__ S, float* __restrict__ ssumOut, int N)
{
  int v = blockIdx.x * 2 + (threadIdx.x >> 6);
  int lane = threadIdx.x & 63;
  if (v >= N) return;
  int begin = offA[v], cnt = cntA[v];
  bool act = lane < 50;
  int kb = act ? 4 * lane : 0;
  float b[4], p[4], pn[4];
  float pw[EE][4];
#pragma unroll
  for (int j = 0; j < 4; ++j) {
    b[j]  = pe1b[kb + j];
    p[j]  = act ? pe2w_e[kb + j] : 0.f;
    pn[j] = act ? pe2w_n[kb + j] : 0.f;
  }
#pragma unroll
  for (int jj = 0; jj < EE; ++jj)
#pragma unroll
    for (int j = 0; j < 4; ++j) pw[jj][j] = pe1w_e[jj * GG + kb + j];

  us4 hv = *(const us4*)(hvnew + (size_t)v * GG + kb);
  float da = bf2f(hv.x) * pn[0] + bf2f(hv.y) * pn[1] + bf2f(hv.z) * pn[2] + bf2f(hv.w) * pn[3];
#pragma unroll
  for (int o = 32; o; o >>= 1) da += __shfl_down(da, o);
  float alv = __shfl(da, 0) + pe2b[0];

  float ss = 0.f;
  float a0 = 0.f, a1 = 0.f, a2 = 0.f, a3 = 0.f;
  int t = 0;
  for (; t + 4 <= cnt; t += 4) {
    int e[4], s[4];
#pragma unroll
    for (int u = 0; u < 4; ++u) {
      e[u] = __builtin_amdgcn_readfirstlane(elist[begin + t + u]);
      s[u] = __builtin_amdgcn_readfirstlane(srcA[e[u]]);
    }
    us4 g[4];
#pragma unroll
    for (int u = 0; u < 4; ++u) g[u] = *(const us4*)(xa + (size_t)s[u] * GG + kb);
    float h[4][4];
#pragma unroll
    for (int u = 0; u < 4; ++u) {
      h[u][0] = bf2f(g[u].x) + b[0];
      h[u][1] = bf2f(g[u].y) + b[1];
      h[u][2] = bf2f(g[u].z) + b[2];
      h[u][3] = bf2f(g[u].w) + b[3];
    }
#pragma unroll
    for (int jj = 0; jj < EE; ++jj) {
#pragma unroll
      for (int u = 0; u < 4; ++u) {
        float x = Xe[(size_t)e[u] * EE + jj];
        h[u][0] += x * pw[jj][0]; h[u][1] += x * pw[jj][1];
        h[u][2] += x * pw[jj][2]; h[u][3] += x * pw[jj][3];
      }
    }
    float bp[4];
#pragma unroll
    for (int u = 0; u < 4; ++u) {
#pragma unroll
      for (int j = 0; j < 4; ++j) h[u][j] = leakyf(h[u][j]);
      bp[u] = h[u][0] * p[0] + h[u][1] * p[1] + h[u][2] * p[2] + h[u][3] * p[3];
    }
#pragma unroll
    for (int o = 32; o; o >>= 1) {
#pragma unroll
      for (int u = 0; u < 4; ++u) bp[u] += __shfl_down(bp[u], o);
    }
#pragma unroll
    for (int u = 0; u < 4; ++u) {
      float w = __expf(fminf(leakyf(alv + __shfl(bp[u], 0)), 60.f));
      ss += w;
      a0 += w * h[u][0]; a1 += w * h[u][1]; a2 += w * h[u][2]; a3 += w * h[u][3];
    }
  }
  for (; t < cnt; ++t) {
    int e0 = __builtin_amdgcn_readfirstlane(elist[begin + t]);
    int s0 = __builtin_amdgcn_readfirstlane(srcA[e0]);
    us4 g0 = *(const us4*)(xa + (size_t)s0 * GG + kb);
    float h0 = bf2f(g0.x) + b[0], h1 = bf2f(g0.y) + b[1];
    float h2 = bf2f(g0.z) + b[2], h3 = bf2f(g0.w) + b[3];
#pragma unroll
    for (int jj = 0; jj < EE; ++jj) {
      float x = Xe[(size_t)e0 * EE + jj];
      h0 += x * pw[jj][0]; h1 += x * pw[jj][1];
      h2 += x * pw[jj][2]; h3 += x * pw[jj][3];
    }
    h0 = leakyf(h0); h1 = leakyf(h1); h2 = leakyf(h2); h3 = leakyf(h3);
    float bp = h0 * p[0] + h1 * p[1] + h2 * p[2] + h3 * p[3];
#pragma unroll
    for (int o = 32; o; o >>= 1) bp += __shfl_down(bp, o);
    float w = __expf(fminf(leakyf(alv + __shfl(bp, 0)), 60.f));
    ss += w;
    a0 += w * h0; a1 += w * h1; a2 += w * h2; a3 += w * h3;
  }
  float inv = (cnt > 0) ? rcp_f(ss) : 0.f;
  if (act) {
    us4 o4;
    o4.x = f2bf(a0 * inv); o4.y = f2bf(a1 * inv);
    o4.z = f2bf(a2 * inv); o4.w = f2bf(a3 * inv);
    *(us4*)(S + (size_t)v * GG + kb) = o4;
  }
  if (lane == 0) ssumOut[v] = (cnt > 0) ? ss : 0.f;
}

// ---------------- layer-2 fused aggregation: 2 nodes per 128-thr block ----------------
__global__ __launch_bounds__(128) void l2_agg(
    const unsigned short* __restrict__ hvp, const float* __restrict__ gd,
    const float* __restrict__ gs, const float* __restrict__ lpeb,
    const int* __restrict__ srcA,
    const int* __restrict__ offA, const int* __restrict__ cntA, const int* __restrict__ elist,
    unsigned short* __restrict__ S2, int N)
{
  int v = blockIdx.x * 2 + (threadIdx.x >> 6);
  int lane = threadIdx.x & 63;
  if (v >= N) return;
  int begin = offA[v], cnt = cntA[v];
  bool act = lane < 50;
  int kb = act ? 4 * lane : 0;
  float gdv = gd[v] + lpeb[0];
  float ss = 0.f;
  float a0 = 0.f, a1 = 0.f, a2 = 0.f, a3 = 0.f;
  int t = 0;
  for (; t + 4 <= cnt; t += 4) {
    int e[4], s[4];
#pragma unroll
    for (int u = 0; u < 4; ++u) {
      e[u] = __builtin_amdgcn_readfirstlane(elist[begin + t + u]);
      s[u] = __builtin_amdgcn_readfirstlane(srcA[e[u]]);
    }
    us4 g0 = *(const us4*)(hvp + (size_t)s[0] * GG + kb);
    us4 g1 = *(const us4*)(hvp + (size_t)s[1] * GG + kb);
    us4 g2 = *(const us4*)(hvp + (size_t)s[2] * GG + kb);
    us4 g3 = *(const us4*)(hvp + (size_t)s[3] * GG + kb);
    float w0 = __expf(fminf(leakyf(gdv + gs[s[0]]), 60.f));
    float w1 = __expf(fminf(leakyf(gdv + gs[s[1]]), 60.f));
    float w2 = __expf(fminf(leakyf(gdv + gs[s[2]]), 60.f));
    float w3 = __expf(fminf(leakyf(gdv + gs[s[3]]), 60.f));
    ss += w0 + w1 + w2 + w3;
    a0 += w0 * bf2f(g0.x) + w1 * bf2f(g1.x) + w2 * bf2f(g2.x) + w3 * bf2f(g3.x);
    a1 += w0 * bf2f(g0.y) + w1 * bf2f(g1.y) + w2 * bf2f(g2.y) + w3 * bf2f(g3.y);
    a2 += w0 * bf2f(g0.z) + w1 * bf2f(g1.z) + w2 * bf2f(g2.z) + w3 * bf2f(g3.z);
    a3 += w0 * bf2f(g0.w) + w1 * bf2f(g1.w) + w2 * bf2f(g2.w) + w3 * bf2f(g3.w);
  }
  for (; t < cnt; ++t) {
    int e = __builtin_amdgcn_readfirstlane(elist[begin + t]);
    int s = __builtin_amdgcn_readfirstlane(srcA[e]);
    us4 g = *(const us4*)(hvp + (size_t)s * GG + kb);
    float w = __expf(fminf(leakyf(gdv + gs[s]), 60.f));
    ss += w;
    a0 += w * bf2f(g.x); a1 += w * bf2f(g.y);
    a2 += w * bf2f(g.z); a3 += w * bf2f(g.w);
  }
  float inv = (cnt > 0) ? rcp_f(ss) : 0.f;
  if (act) {
    us4 o4;
    o4.x = f2bf((cnt > 0) ? elu_fast(a0 * inv) : 0.f);
    o4.y = f2bf((cnt > 0) ? elu_fast(a1 * inv) : 0.f);
    o4.z = f2bf((cnt > 0) ? elu_fast(a2 * inv) : 0.f);
    o4.w = f2bf((cnt > 0) ? elu_fast(a3 * inv) : 0.f);
    *(us4*)(S2 + (size_t)v * GG + kb) = o4;
  }
}

// ================= direct-from-L2 MFMA GEMM, packed-B =================
template <int NKC>
__global__ __launch_bounds__(256, 2) void mfma_gemm_d(
    const unsigned short* __restrict__ A, int strideA,
    const unsigned short* __restrict__ Wp,
    const float* __restrict__ bias, const float* __restrict__ rowmask,
    unsigned short* __restrict__ Cb, int Mr, int Nc, int act)
{
  int ncol = (Nc + 63) >> 6;
  int nrowt = (Mr + 127) >> 7;
  int per = 8 * ncol;
  int grp = blockIdx.x / per, rem = blockIdx.x % per;
  int rowt = grp * 8 + (rem & 7), colt = rem >> 3;
  if (rowt >= nrowt) return;
  int row0 = rowt * 128, col0 = colt * 64;
  int tid = threadIdx.x;
  int w = tid >> 6, lane = tid & 63, quad = lane >> 4, l15 = lane & 15;

  int rA0 = min(row0 + w * 32 + l15, Mr - 1);
  int rA1 = min(row0 + w * 32 + 16 + l15, Mr - 1);
  const unsigned short* pA0 = A + (size_t)rA0 * strideA + quad * 8;
  const unsigned short* pA1 = A + (size_t)rA1 * strideA + quad * 8;
  const unsigned short* pB[4];
#pragma unroll
  for (int c = 0; c < 4; ++c)
    pB[c] = Wp + ((size_t)(colt * 4 + c) * NKC) * 512 + lane * 8;

  f32x4 zero4 = {0.f, 0.f, 0.f, 0.f};
  f32x4 acc[2][4];
#pragma unroll
  for (int r = 0; r < 2; ++r)
#pragma unroll
    for (int c = 0; c < 4; ++c) acc[r][c] = zero4;

#pragma unroll
  for (int kc = 0; kc < NKC; ++kc) {
    bf16x8 a0 = *(const bf16x8*)(pA0 + kc * 32);
    bf16x8 a1 = *(const bf16x8*)(pA1 + kc * 32);
    bf16x8 b[4];
#pragma unroll
    for (int c = 0; c < 4; ++c) b[c] = *(const bf16x8*)(pB[c] + kc * 512);
#pragma unroll
    for (int c = 0; c < 4; ++c) {
      acc[0][c] = __builtin_amdgcn_mfma_f32_16x16x32_bf16(a0, b[c], acc[0][c], 0, 0, 0);
      acc[1][c] = __builtin_amdgcn_mfma_f32_16x16x32_bf16(a1, b[c], acc[1][c], 0, 0, 0);
    }
  }
#pragma unroll
  for (int r = 0; r < 2; ++r) {
#pragma unroll
    for (int c = 0; c < 4; ++c) {
      int col = col0 + c * 16 + l15;
      if (col >= Nc) continue;
#pragma unroll
      for (int i = 0; i < 4; ++i) {
        int row = row0 + w * 32 + r * 16 + quad * 4 + i;
        if (row >= Mr) continue;
        bool valid = (rowmask == nullptr) || (rowmask[row] > 0.f);
        float v = valid ? (acc[r][c][i] + (bias ? bias[col] : 0.f)) : 0.f;
        if (act == 1) v = leakyf(v);
        else if (act == 2) v = elu_fast(v);
        Cb[(size_t)row * Nc + col] = f2bf(v);
      }
    }
  }
}

// ================= direct-from-L2 fused MFMA GRU, packed-B =================
template <typename TI, typename TO>
__global__ __launch_bounds__(256, 2) void mfma_gru_d(
    const TI* __restrict__ X, const TI* __restrict__ H,
    const unsigned short* __restrict__ WIHp, const unsigned short* __restrict__ WHHp,
    const float* __restrict__ bih, const float* __restrict__ bhh,
    TO* __restrict__ Out, int R, int relu_out)
{
  int nrowt = (R + 127) >> 7;
  int grp = blockIdx.x / 56, rem = blockIdx.x % 56;
  int rowt = grp * 8 + (rem & 7), colt = rem >> 3;
  if (rowt >= nrowt) return;
  int row0 = rowt * 128, col0 = colt * 32;
  int tid = threadIdx.x;
  int w = tid >> 6, lane = tid & 63, quad = lane >> 4, l15 = lane & 15;

  int rA0 = min(row0 + w * 32 + l15, R - 1);
  int rA1 = min(row0 + w * 32 + 16 + l15, R - 1);
  const TI* pX0 = X + (size_t)rA0 * GG + quad * 8;
  const TI* pX1 = X + (size_t)rA1 * GG + quad * 8;
  const TI* pH0 = H + (size_t)rA0 * GG + quad * 8;
  const TI* pH1 = H + (size_t)rA1 * GG + quad * 8;
  const unsigned short* pBi[3][2];
  const unsigned short* pBh[3][2];
#pragma unroll
  for (int g = 0; g < 3; ++g)
#pragma unroll
    for (int c = 0; c < 2; ++c) {
      size_t tileoff = ((size_t)(g * 14 + colt * 2 + c) * 7) * 512 + lane * 8;
      pBi[g][c] = WIHp + tileoff;
      pBh[g][c] = WHHp + tileoff;
    }

  f32x4 zero4 = {0.f, 0.f, 0.f, 0.f};
  f32x4 acc[6][2][2];
#pragma unroll
  for (int g = 0; g < 6; ++g)
#pragma unroll
    for (int r = 0; r < 2; ++r)
#pragma unroll
      for (int c = 0; c < 2; ++c) acc[g][r][c] = zero4;

#pragma unroll
  for (int kc = 0; kc < 7; ++kc) {
    bf16x8 ax0 = afrag(pX0, kc * 32);
    bf16x8 ax1 = afrag(pX1, kc * 32);
    bf16x8 ah0 = afrag(pH0, kc * 32);
    bf16x8 ah1 = afrag(pH1, kc * 32);
#pragma unroll
    for (int g = 0; g < 3; ++g) {
      bf16x8 bi0 = *(const bf16x8*)(pBi[g][0] + kc * 512);
      bf16x8 bi1 = *(const bf16x8*)(pBi[g][1] + kc * 512);
      bf16x8 bh0 = *(const bf16x8*)(pBh[g][0] + kc * 512);
      bf16x8 bh1 = *(const bf16x8*)(pBh[g][1] + kc * 512);
      acc[g][0][0] = __builtin_amdgcn_mfma_f32_16x16x32_bf16(ax0, bi0, acc[g][0][0], 0, 0, 0);
      acc[g][0][1] = __builtin_amdgcn_mfma_f32_16x16x32_bf16(ax0, bi1, acc[g][0][1], 0, 0, 0);
      acc[g][1][0] = __builtin_amdgcn_mfma_f32_16x16x32_bf16(ax1, bi0, acc[g][1][0], 0, 0, 0);
      acc[g][1][1] = __builtin_amdgcn_mfma_f32_16x16x32_bf16(ax1, bi1, acc[g][1][1], 0, 0, 0);
      acc[g + 3][0][0] = __builtin_amdgcn_mfma_f32_16x16x32_bf16(ah0, bh0, acc[g + 3][0][0], 0, 0, 0);
      acc[g + 3][0][1] = __builtin_amdgcn_mfma_f32_16x16x32_bf16(ah0, bh1, acc[g + 3][0][1], 0, 0, 0);
      acc[g + 3][1][0] = __builtin_amdgcn_mfma_f32_16x16x32_bf16(ah1, bh0, acc[g + 3][1][0], 0, 0, 0);
      acc[g + 3][1][1] = __builtin_amdgcn_mfma_f32_16x16x32_bf16(ah1, bh1, acc[g + 3][1][1], 0, 0, 0);
    }
  }
#pragma unroll
  for (int r = 0; r < 2; ++r) {
#pragma unroll
    for (int c = 0; c < 2; ++c) {
      int col = col0 + c * 16 + l15;
      if (col >= GG) continue;
      float br = bih[col],       bhr = bhh[col];
      float bz = bih[200 + col], bhz = bhh[200 + col];
      float bn = bih[400 + col], bhn = bhh[400 + col];
#pragma unroll
      for (int i = 0; i < 4; ++i) {
        int row = row0 + w * 32 + r * 16 + quad * 4 + i;
        if (row >= R) continue;
        float rr = sigm_fast(acc[0][r][c][i] + br + acc[3][r][c][i] + bhr);
        float zz = sigm_fast(acc[1][r][c][i] + bz + acc[4][r][c][i] + bhz);
        float nn = tanh_fast(acc[2][r][c][i] + bn + rr * (acc[5][r][c][i] + bhn));
        float hval = ldv<TI>(H + (size_t)row * GG + col);
        float o = (1.f - zz) * nn + zz * hval;
        if (relu_out) o = fmaxf(o, 0.f);
        if constexpr (sizeof(TO) == 2) Out[(size_t)row * GG + col] = f2bf(o);
        else Out[(size_t)row * GG + col] = o;
      }
    }
  }
}

// ---------------- fp32 tiled GEMM (small readout shapes) ----------------
#define Bb 64
#define Bn 64
#define Bk 16
__global__ __launch_bounds__(256) void gemm_kernel(
    const float* __restrict__ A, const float* __restrict__ W,
    const float* __restrict__ bias, const float* __restrict__ rowmask,
    float* __restrict__ Cf, void* __restrict__ Oout, const int* __restrict__ oflag,
    int Mr, int Nc, int K, int act)
{
  __shared__ float As[Bk][Bb + 1];
  __shared__ float Ws[Bk][Bn];
  int row0 = blockIdx.x * Bb, col0 = blockIdx.y * Bn;
  int tid = threadIdx.x;
  int ty = tid >> 4, tx = tid & 15;
  float acc[4][4] = {};
  for (int k0 = 0; k0 < K; k0 += Bk) {
    for (int l = tid; l < Bb * Bk; l += 256) {
      int m = l >> 4, kk = l & 15;
      int r = row0 + m, k = k0 + kk;
      As[kk][m] = (r < Mr && k < K) ? A[(size_t)r * K + k] : 0.f;
    }
    for (int l = tid; l < Bk * Bn; l += 256) {
      int kk = l >> 6, nn = l & 63;
      int k = k0 + kk, c = col0 + nn;
      Ws[kk][nn] = (k < K && c < Nc) ? W[(size_t)k * Nc + c] : 0.f;
    }
    __syncthreads();
#pragma unroll
    for (int kk = 0; kk < Bk; ++kk) {
      float av[4], bv[4];
#pragma unroll
      for (int i = 0; i < 4; ++i) av[i] = As[kk][ty * 4 + i];
#pragma unroll
      for (int j = 0; j < 4; ++j) bv[j] = Ws[kk][tx * 4 + j];
#pragma unroll
      for (int i = 0; i < 4; ++i)
#pragma unroll
        for (int j = 0; j < 4; ++j) acc[i][j] += av[i] * bv[j];
    }
    __syncthreads();
  }
  int isbf = (oflag != nullptr) ? *oflag : 0;
#pragma unroll
  for (int i = 0; i < 4; ++i) {
    int r = row0 + ty * 4 + i;
    if (r >= Mr) continue;
    bool valid = (rowmask == nullptr) || (rowmask[r] > 0.f);
#pragma unroll
    for (int j = 0; j < 4; ++j) {
      int c = col0 + tx * 4 + j;
      if (c >= Nc) continue;
      float v = valid ? (acc[i][j] + (bias ? bias[c] : 0.f)) : 0.f;
      if (act == 1) v = leakyf(v);
      else if (act == 2) v = elu_fast(v);
      else if (act == 3) v = fmaxf(v, 0.f);
      size_t idx = (size_t)r * Nc + c;
      if (Oout) {
        if (isbf) ((__hip_bfloat16*)Oout)[idx] = __float2bfloat16(v);
        else      ((float*)Oout)[idx] = v;
      } else {
        Cf[idx] = v;
      }
    }
  }
}

// ---------------- per-node dot(s), bf16 input ----------------
__global__ __launch_bounds__(256) void node_dot2(
    const unsigned short* __restrict__ X, const float* __restrict__ w1,
    const float* __restrict__ w2,
    float* __restrict__ o1, float* __restrict__ o2, int N)
{
  int v = (blockIdx.x * 256 + threadIdx.x) >> 6;
  int lane = threadIdx.x & 63;
  if (v >= N) return;
  float d1 = 0.f, d2 = 0.f;
  for (int k = lane; k < GG; k += 64) {
    float x = bf2f(X[(size_t)v * GG + k]);
    d1 += x * w1[k];
    if (w2) d2 += x * w2[k];
  }
  for (int off = 32; off; off >>= 1) {
    d1 += __shfl_down(d1, off);
    if (w2) d2 += __shfl_down(d2, off);
  }
  if (lane == 0) { o1[v] = d1; if (w2) o2[v] = d2; }
}

__global__ __launch_bounds__(256) void graph_sum(
    const unsigned short* __restrict__ h, float* __restrict__ g)
{
  int b = blockIdx.x, k = threadIdx.x;
  if (k < GG) {
    float a = 0.f;
    for (int i = 0; i < 50; ++i) a += bf2f(h[((size_t)b * 50 + i) * GG + k]);
    g[(size_t)b * GG + k] = a;
  }
}

__global__ __launch_bounds__(256) void attn_kernel(
    const float* __restrict__ g, const unsigned short* __restrict__ h2,
    const float* __restrict__ w1, const float* __restrict__ dh,
    const float* __restrict__ rb, float* __restrict__ weighted)
{
  int b = blockIdx.x;
  __shared__ float red[256];
  __shared__ float zs[50];
  __shared__ float as_[50];
  __shared__ float dgs;
  int tid = threadIdx.x;
  float p = 0.f;
  if (tid < GG) p = fmaxf(g[(size_t)b * GG + tid], 0.f) * w1[tid];
  red[tid] = p;
  __syncthreads();
  for (int s = 128; s; s >>= 1) { if (tid < s) red[tid] += red[tid + s]; __syncthreads(); }
  if (tid == 0) dgs = red[0];
  __syncthreads();
  if (tid < 50) zs[tid] = leakyf(dgs + dh[b * 50 + tid] + rb[0]);
  __syncthreads();
  if (tid == 0) {
    float m = -1e30f;
    for (int i = 0; i < 50; ++i) m = fmaxf(m, zs[i]);
    float s = 0.f;
    for (int i = 0; i < 50; ++i) { float e = __expf(zs[i] - m); as_[i] = e; s += e; }
    float inv = 1.f / s;
    for (int i = 0; i < 50; ++i) as_[i] *= inv;
  }
  __syncthreads();
  if (tid < GG) {
    float a = 0.f;
    for (int i = 0; i < 50; ++i) a += as_[i] * bf2f(h2[((size_t)b * 50 + i) * GG + tid]);
    weighted[(size_t)b * GG + tid] = a;
  }
}

// ---------------- host ----------------
static inline int gemm_grid(int Mr, int Nc) {
  int nrow = (Mr + 127) / 128, ncol = (Nc + 63) / 64;
  return ((nrow + 7) / 8) * 8 * ncol;
}
static inline int gru_grid(int R) {
  int nrow = (R + 127) / 128;
  return ((nrow + 7) / 8) * 56;
}

extern "C" void kernel_launch(void* const* d_in, const int* in_sizes, int n_in,
                              void* d_out, int out_size, void* d_ws, size_t ws_size,
                              hipStream_t stream)
{
  (void)n_in; (void)out_size; (void)ws_size;
  const int N = NN, M = MM, B = BB, F = FF, G = GG, P = PP;
  const int PK7 = 14 * 7 * 512, PK2 = 14 * 2 * 512;
  float* ws = (float*)d_ws;
  size_t off = 0;
  auto alloc = [&](size_t n) { size_t o = off; off += (n + 63) & ~(size_t)63; return o; };

  size_t o_flag = alloc(16);
  size_t o_pn_w = alloc(F * G), o_pn_b = alloc(G);
  size_t o_pe1_w = alloc((F + EE) * G), o_pe1_b = alloc(G);
  size_t o_pe2_w = alloc(2 * G), o_pe2_b = alloc(1);
  size_t o_et_w = alloc(G * G), o_et_b = alloc(G);
  size_t o_g0_wih = alloc(G * 3 * G), o_g0_whh = alloc(G * 3 * G);
  size_t o_g0_bih = alloc(3 * G), o_g0_bhh = alloc(3 * G);
  size_t o_lpe_w = alloc(2 * G), o_lpe_b = alloc(1);
  size_t o_lpn_w = alloc(G * G), o_lpn_b = alloc(G);
  size_t o_g1_wih = alloc(G * 3 * G), o_g1_whh = alloc(G * 3 * G);
  size_t o_g1_bih = alloc(3 * G), o_g1_bhh = alloc(3 * G);
  size_t o_rl_w = alloc(2 * 2 * G), o_rl_b = alloc(2);
  size_t o_rp_w = alloc(2 * G * G), o_rp_b = alloc(2 * G);
  size_t o_rg_wih = alloc(2 * G * 3 * G), o_rg_whh = alloc(2 * G * 3 * G);
  size_t o_rg_bih = alloc(2 * 3 * G), o_rg_bhh = alloc(2 * 3 * G);
  size_t o_t_w = alloc(G * P), o_t_b = alloc(P);
  size_t o_Xnb = alloc((size_t)N * 40 / 2 + 64);
  size_t o_Xe = alloc((size_t)M * EE);
  size_t o_B1 = alloc((size_t)N * G);
  size_t o_B2 = alloc((size_t)N * G);
  size_t o_B3 = alloc((size_t)N * G);
  size_t o_ssum = alloc(N);
  size_t o_gd = alloc(N), o_gs = alloc(N), o_dh = alloc(N);
  size_t o_gv0 = alloc((size_t)B * G), o_gwt = alloc((size_t)B * G), o_grep = alloc((size_t)B * G + 64);
  size_t o_gv1 = alloc((size_t)B * G + 64), o_gv2 = alloc((size_t)B * G + 64);
  size_t o_etP  = alloc(PK7 / 2 + 64), o_lpnP = alloc(PK7 / 2 + 64);
  size_t o_g0ihP = alloc(3 * PK7 / 2 + 64), o_g0hhP = alloc(3 * PK7 / 2 + 64);
  size_t o_g1ihP = alloc(3 * PK7 / 2 + 64), o_g1hhP = alloc(3 * PK7 / 2 + 64);
  size_t o_rg0ihP = alloc(3 * PK7 / 2 + 64), o_rg0hhP = alloc(3 * PK7 / 2 + 64);
  size_t o_rg1ihP = alloc(3 * PK7 / 2 + 64), o_rg1hhP = alloc(3 * PK7 / 2 + 64);
  size_t o_pnP = alloc(PK2 / 2 + 64), o_pe1P = alloc(PK2 / 2 + 64);
  size_t o_cnt = alloc(N), o_off = alloc(N), o_cur = alloc(N);
  size_t o_elist = alloc(M), o_bsum = alloc(64), o_incl = alloc(N);

  int* flag = (int*)(ws + o_flag);
  int* cntA = (int*)(ws + o_cnt);
  int* offA = (int*)(ws + o_off);
  int* curA = (int*)(ws + o_cur);
  int* elist = (int*)(ws + o_elist);
  int* bsum = (int*)(ws + o_bsum);
  int* incl = (int*)(ws + o_incl);
  unsigned short* Xnb = (unsigned short*)(ws + o_Xnb);
  unsigned short* B1b = (unsigned short*)(ws + o_B1);
  unsigned short* B2b = (unsigned short*)(ws + o_B2);
  unsigned short* B3b = (unsigned short*)(ws + o_B3);

  CvtJobs32 jobs;
  int ji = 0;
  auto push = [&](int idx, size_t dsto) {
    jobs.j[ji].s = d_in[idx];
    jobs.j[ji].d = ws + dsto;
    jobs.j[ji].n = in_sizes[idx];
    jobs.j[ji].pad = 0;
    ++ji;
  };
  push(1, o_Xe);
  push(2, o_pn_w);  push(3, o_pn_b);
  push(4, o_pe1_w); push(5, o_pe1_b);
  push(6, o_pe2_w); push(7, o_pe2_b);
  push(8, o_et_w);  push(9, o_et_b);
  push(10, o_g0_wih); push(11, o_g0_whh); push(12, o_g0_bih); push(13, o_g0_bhh);
  push(14, o_lpe_w);  push(15, o_lpe_b);
  push(16, o_lpn_w);  push(17, o_lpn_b);
  push(18, o_g1_wih); push(19, o_g1_whh); push(20, o_g1_bih); push(21, o_g1_bhh);
  push(22, o_rl_w);   push(23, o_rl_b);
  push(24, o_rp_w);   push(25, o_rp_b);
  push(26, o_rg_wih); push(27, o_rg_whh); push(28, o_rg_bih); push(29, o_rg_bhh);
  push(30, o_t_w);    push(31, o_t_b);

  const int* src = (const int*)d_in[32];
  const int* dst = (const int*)d_in[33];

  dim3 blk(256);
  detect_dtype<<<dim3(1), blk, 0, stream>>>((const unsigned int*)d_in[0], flag);
  cvt_any<<<dim3(512, 31), blk, 0, stream>>>(jobs, flag);
  cvt_xn<<<dim3((N * 40 + 255) / 256), blk, 0, stream>>>(d_in[0], Xnb, flag, N);

  // ---- CSR build (by dst) ----
  hipMemsetAsync(cntA, 0, (size_t)N * 4, stream);
  hist_kernel<<<dim3((M + 255) / 256), blk, 0, stream>>>(dst, cntA, M);
  int nscb = (N + SCHUNK - 1) / SCHUNK;
  scan1_kernel<<<dim3(nscb), blk, 0, stream>>>(cntA, incl, bsum, N);
  scan2_kernel<<<dim3(1), dim3(64), 0, stream>>>(bsum, nscb);
  scan3_kernel<<<dim3((N + 255) / 256), blk, 0, stream>>>(incl, cntA, bsum, offA, curA, N);
  fill_kernel<<<dim3((M + 255) / 256), blk, 0, stream>>>(dst, curA, elist, M);

  // ---- weight packing (fragment-major) ----
  PJobs28 pj;
  int pi = 0;
  auto ppush = [&](size_t srcO, size_t dstOshorts_base, int slot_shorts, int K, int Ns, int coff, int nkc) {
    pj.j[pi].s = ws + srcO;
    pj.j[pi].d = (unsigned short*)(ws + dstOshorts_base) + slot_shorts;
    pj.j[pi].K = K; pj.j[pi].Ns = Ns; pj.j[pi].coff = coff; pj.j[pi].nkc = nkc;
    ++pi;
  };
  ppush(o_et_w,  o_etP,  0, G, G, 0, 7);
  ppush(o_lpn_w, o_lpnP, 0, G, G, 0, 7);
  for (int g = 0; g < 3; ++g) {
    ppush(o_g0_wih, o_g0ihP, g * PK7, G, 3 * G, g * G, 7);
    ppush(o_g0_whh, o_g0hhP, g * PK7, G, 3 * G, g * G, 7);
    ppush(o_g1_wih, o_g1ihP, g * PK7, G, 3 * G, g * G, 7);
    ppush(o_g1_whh, o_g1hhP, g * PK7, G, 3 * G, g * G, 7);
    ppush(o_rg_wih, o_rg0ihP, g * PK7, G, 3 * G, g * G, 7);
    ppush(o_rg_whh, o_rg0hhP, g * PK7, G, 3 * G, g * G, 7);
    ppush(o_rg_wih + (size_t)G * 3 * G, o_rg1ihP, g * PK7, G, 3 * G, g * G, 7);
    ppush(o_rg_whh + (size_t)G * 3 * G, o_rg1hhP, g * PK7, G, 3 * G, g * G, 7);
  }
  ppush(o_pn_w,  o_pnP,  0, F, G, 0, 2);
  ppush(o_pe1_w, o_pe1P, 0, F, G, 0, 2);
  pack_bf16<<<dim3(64, 28), blk, 0, stream>>>(pj);

  int gg = gemm_grid(N, G);
  mfma_gemm_d<2><<<dim3(gg), blk, 0, stream>>>(
      Xnb, 40, (const unsigned short*)(ws + o_pnP),
      ws + o_pn_b, nullptr, B1b, N, G, 1);
  mfma_gemm_d<2><<<dim3(gg), blk, 0, stream>>>(
      Xnb, 40, (const unsigned short*)(ws + o_pe1P),
      nullptr, nullptr, B2b, N, G, 0);
  l1_agg<<<dim3((N + 1) / 2), dim3(128), 0, stream>>>(ws + o_Xe, B2b, B1b,
                                           ws + o_pe1_w + (size_t)F * G, ws + o_pe1_b,
                                           ws + o_pe2_w, ws + o_pe2_w + G, ws + o_pe2_b,
                                           src, offA, cntA, elist,
                                           B3b, ws + o_ssum, N);
  mfma_gemm_d<7><<<dim3(gg), blk, 0, stream>>>(
      B3b, G, (const unsigned short*)(ws + o_etP),
      ws + o_et_b, ws + o_ssum, B2b, N, G, 2);
  mfma_gru_d<unsigned short, unsigned short><<<dim3(gru_grid(N)), blk, 0, stream>>>(
      B2b, B1b,
      (const unsigned short*)(ws + o_g0ihP), (const unsigned short*)(ws + o_g0hhP),
      ws + o_g0_bih, ws + o_g0_bhh, B3b, N, 1);

  // ---- layer 2 ----
  dim3 gWave((N + 3) / 4);
  node_dot2<<<gWave, blk, 0, stream>>>(B3b, ws + o_lpe_w, ws + o_lpe_w + G,
                                       ws + o_gd, ws + o_gs, N);
  mfma_gemm_d<7><<<dim3(gg), blk, 0, stream>>>(
      B3b, G, (const unsigned short*)(ws + o_lpnP),
      ws + o_lpn_b, nullptr, B1b, N, G, 0);
  l2_agg<<<dim3((N + 1) / 2), dim3(128), 0, stream>>>(B1b, ws + o_gd, ws + o_gs, ws + o_lpe_b,
                                           src, offA, cntA, elist, B2b, N);
  mfma_gru_d<unsigned short, unsigned short><<<dim3(gru_grid(N)), blk, 0, stream>>>(
      B2b, B3b,
      (const unsigned short*)(ws + o_g1ihP), (const unsigned short*)(ws + o_g1hhP),
      ws + o_g1_bih, ws + o_g1_bhh, B1b, N, 1);

  // ---- readout ----
  graph_sum<<<dim3(B), blk, 0, stream>>>(B1b, ws + o_gv0);
  dim3 gBG((B + Bb - 1) / Bb, (G + Bn - 1) / Bn);
  size_t gcur = o_gv0, gnext = o_gv1;
  for (int t = 0; t < 2; ++t) {
    node_dot2<<<gWave, blk, 0, stream>>>(B1b, ws + o_rl_w + t * 2 * G + G,
                                         nullptr, ws + o_dh, nullptr, N);
    attn_kernel<<<dim3(B), blk, 0, stream>>>(ws + gcur, B1b, ws + o_rl_w + t * 2 * G,
                                             ws + o_dh, ws + o_rl_b + t, ws + o_gwt);
    gemm_kernel<<<gBG, blk, 0, stream>>>(ws + o_gwt, ws + o_rp_w + (size_t)t * G * G,
                                         ws + o_rp_b + t * G, nullptr,
                                         ws + o_grep, nullptr, nullptr, B, G, G, 2);
    mfma_gru_d<float, float><<<dim3(gru_grid(B)), blk, 0, stream>>>(
        ws + o_grep, ws + gcur,
        (const unsigned short*)(ws + (t == 0 ? o_rg0ihP : o_rg1ihP)),
        (const unsigned short*)(ws + (t == 0 ? o_rg0hhP : o_rg1hhP)),
        ws + o_rg_bih + t * 3 * G, ws + o_rg_bhh + t * 3 * G,
        ws + gnext, B, 0);
    gcur = gnext;
    gnext = o_gv2;
  }
  dim3 gOut((B + Bb - 1) / Bb, (P + Bn - 1) / Bn);
  gemm_kernel<<<gOut, blk, 0, stream>>>(ws + gcur, ws + o_t_w, ws + o_t_b, nullptr,
                                        nullptr, d_out, flag, B, P, G, 0);
}

// Round 13
// 822.371 us; speedup vs baseline: 1.0068x; 1.0068x over previous
//
#include <hip/hip_runtime.h>
#include <hip/hip_bf16.h>

// ---------------- constants ----------------
#define NN 50000
#define MM 400000
#define BB 1000
#define FF 39
#define EE 11
#define GG 200
#define PP 128

typedef __attribute__((ext_vector_type(8))) short bf16x8;
typedef __attribute__((ext_vector_type(4))) float f32x4;
struct us4 { unsigned short x, y, z, w; };

// ---------------- helpers ----------------
__device__ __forceinline__ float bf2f(unsigned short u) {
  return __uint_as_float(((unsigned int)u) << 16);
}
__device__ __forceinline__ unsigned short f2bf(float x) {
  union { __hip_bfloat16 b; unsigned short u; } v;
  v.b = __float2bfloat16(x);
  return v.u;
}
__device__ __forceinline__ float rcp_f(float x) { return __builtin_amdgcn_rcpf(x); }
__device__ __forceinline__ float leakyf(float x) { return x > 0.f ? x : 0.01f * x; }
__device__ __forceinline__ float elu_fast(float x)  { return x > 0.f ? x : __expf(x) - 1.f; }
__device__ __forceinline__ float sigm_fast(float x) { return rcp_f(1.f + __expf(-x)); }
__device__ __forceinline__ float tanh_fast(float x) { return 1.f - 2.f * rcp_f(1.f + __expf(2.f * x)); }
template <typename T> __device__ __forceinline__ float ldv(const T* p);
template <> __device__ __forceinline__ float ldv<float>(const float* p) { return *p; }
template <> __device__ __forceinline__ float ldv<unsigned short>(const unsigned short* p) { return bf2f(*p); }

// direct global A-fragment load: 8 consecutive elements (row layout)
template <typename T>
__device__ __forceinline__ bf16x8 afrag(const T* base, size_t off) {
  if constexpr (sizeof(T) == 2) {
    return *(const bf16x8*)(base + off);
  } else {
    float4 f0 = *(const float4*)(base + off);
    float4 f1 = *(const float4*)(base + off + 4);
    short t[8];
    t[0] = (short)f2bf(f0.x); t[1] = (short)f2bf(f0.y);
    t[2] = (short)f2bf(f0.z); t[3] = (short)f2bf(f0.w);
    t[4] = (short)f2bf(f1.x); t[5] = (short)f2bf(f1.y);
    t[6] = (short)f2bf(f1.z); t[7] = (short)f2bf(f1.w);
    return *(bf16x8*)t;
  }
}

// ---------------- runtime dtype detection ----------------
__global__ __launch_bounds__(256) void detect_dtype(const unsigned int* __restrict__ w,
                                                    int* __restrict__ flag) {
  __shared__ int cnt[256];
  int c = 0;
  for (int i = threadIdx.x; i < 2048; i += 256) {
    unsigned int e = (w[i] >> 8) & 0x7F;
    c += (e >= 60 && e <= 64) ? 1 : 0;
  }
  cnt[threadIdx.x] = c;
  __syncthreads();
  for (int s = 128; s; s >>= 1) {
    if (threadIdx.x < s) cnt[threadIdx.x] += cnt[threadIdx.x + s];
    __syncthreads();
  }
  if (threadIdx.x == 0) *flag = (cnt[0] >= 1024) ? 1 : 0;
}

// ---------------- batched conversion to f32 ----------------
struct CvtJob { const void* s; float* d; int n; int pad; };
struct CvtJobs32 { CvtJob j[32]; };

__global__ __launch_bounds__(256) void cvt_any(CvtJobs32 jobs, const int* __restrict__ flag) {
  CvtJob job = jobs.j[blockIdx.y];
  int isbf = *flag;
  if (isbf) {
    const unsigned short* s = (const unsigned short*)job.s;
    for (int i = blockIdx.x * 256 + threadIdx.x; i < job.n; i += gridDim.x * 256)
      job.d[i] = bf2f(s[i]);
  } else {
    const float* s = (const float*)job.s;
    for (int i = blockIdx.x * 256 + threadIdx.x; i < job.n; i += gridDim.x * 256)
      job.d[i] = s[i];
  }
}

// Xn -> bf16 padded [N][40]
__global__ __launch_bounds__(256) void cvt_xn(const void* __restrict__ src,
                                              unsigned short* __restrict__ dstb,
                                              const int* __restrict__ flag, int N) {
  int isbf = *flag;
  int total = N * 40;
  for (int i = blockIdx.x * 256 + threadIdx.x; i < total; i += gridDim.x * 256) {
    int n = i / 40, k = i - n * 40;
    unsigned short v = 0;
    if (k < FF) {
      if (isbf) v = ((const unsigned short*)src)[n * FF + k];
      else      v = f2bf(((const float*)src)[n * FF + k]);
    }
    dstb[i] = v;
  }
}

// ---------------- fragment-major weight pack ----------------
struct PJob { const float* s; unsigned short* d; int K; int Ns; int coff; int nkc; };
struct PJobs28 { PJob j[28]; };

__global__ __launch_bounds__(256) void pack_bf16(PJobs28 jobs) {
  PJob job = jobs.j[blockIdx.y];
  int per = job.nkc * 512;
  int total = 14 * per;
  for (int idx = blockIdx.x * 256 + threadIdx.x; idx < total; idx += gridDim.x * 256) {
    int ct = idx / per, r = idx - ct * per;
    int kc = r >> 9, e = r & 511;
    int lane = e >> 3, j = e & 7;
    int n = ct * 16 + (lane & 15);
    int k = kc * 32 + (lane >> 4) * 8 + j;
    job.d[idx] = (k < job.K && n < GG)
        ? f2bf(job.s[(size_t)k * job.Ns + job.coff + n]) : (unsigned short)0;
  }
}

// ---------------- CSR build ----------------
__global__ __launch_bounds__(256) void hist_kernel(const int* __restrict__ dst,
                                                   int* __restrict__ cnt, int M) {
  int e = blockIdx.x * 256 + threadIdx.x;
  if (e < M) atomicAdd(&cnt[dst[e]], 1);
}

#define SCHUNK 2048
__global__ __launch_bounds__(256) void scan1_kernel(const int* __restrict__ cnt,
                                                    int* __restrict__ incl,
                                                    int* __restrict__ bsum, int n) {
  __shared__ int lds[256];
  int b = blockIdx.x, tid = threadIdx.x;
  int base = b * SCHUNK + tid * 8;
  int v[8], s = 0;
#pragma unroll
  for (int j = 0; j < 8; ++j) { int i = base + j; v[j] = (i < n) ? cnt[i] : 0; s += v[j]; }
  lds[tid] = s;
  __syncthreads();
  for (int o = 1; o < 256; o <<= 1) {
    int t = (tid >= o) ? lds[tid - o] : 0;
    __syncthreads();
    lds[tid] += t;
    __syncthreads();
  }
  int run = lds[tid] - s;
#pragma unroll
  for (int j = 0; j < 8; ++j) {
    run += v[j];
    int i = base + j;
    if (i < n) incl[i] = run;
  }
  if (tid == 255) bsum[b] = lds[255];
}

__global__ void scan2_kernel(int* __restrict__ bsum, int nb) {
  if (threadIdx.x == 0 && blockIdx.x == 0) {
    int run = 0;
    for (int i = 0; i < nb; ++i) { int t = bsum[i]; bsum[i] = run; run += t; }
  }
}

__global__ __launch_bounds__(256) void scan3_kernel(const int* __restrict__ incl,
                                                    const int* __restrict__ cnt,
                                                    const int* __restrict__ bsum,
                                                    int* __restrict__ offA,
                                                    int* __restrict__ cur, int n) {
  int i = blockIdx.x * 256 + threadIdx.x;
  if (i >= n) return;
  int o = incl[i] - cnt[i] + bsum[i / SCHUNK];
  offA[i] = o;
  cur[i] = o;
}

__global__ __launch_bounds__(256) void fill_kernel(const int* __restrict__ dst,
                                                   int* __restrict__ cur,
                                                   int* __restrict__ elist, int M) {
  int e = blockIdx.x * 256 + threadIdx.x;
  if (e >= M) return;
  int pos = atomicAdd(&cur[dst[e]], 1);
  elist[pos] = e;
}

// ---------------- layer-1 fused aggregation: persistent waves ----------------
// 4 independent waves per 256-thr block; each wave grid-strides over nodes.
__global__ __launch_bounds__(256) void l1_agg(
    const float* __restrict__ Xe, const unsigned short* __restrict__ xa,
    const unsigned short* __restrict__ hvnew,
    const float* __restrict__ pe1w_e, const float* __restrict__ pe1b,
    const float* __restrict__ pe2w_n, const float* __restrict__ pe2w_e,
    const float* __restrict__ pe2b, const int* __restrict__ srcA,
    const int* __restrict__ offA, const int* __restrict__ cntA, const int* __restrict__ elist,
    unsigned short* __restrict__ S, float* __restrict__ ssumOut, int N, int nwaves)
{
  int wid = blockIdx.x * 4 + (threadIdx.x >> 6);
  int lane = threadIdx.x & 63;
  bool act = lane < 50;
  int kb = act ? 4 * lane : 0;
  // per-lane constants hoisted out of the node loop
  float b[4], p[4], pn[4];
  float pw[EE][4];
#pragma unroll
  for (int j = 0; j < 4; ++j) {
    b[j]  = pe1b[kb + j];
    p[j]  = act ? pe2w_e[kb + j] : 0.f;
    pn[j] = act ? pe2w_n[kb + j] : 0.f;
  }
#pragma unroll
  for (int jj = 0; jj < EE; ++jj)
#pragma unroll
    for (int j = 0; j < 4; ++j) pw[jj][j] = pe1w_e[jj * GG + kb + j];
  float pe2b0 = pe2b[0];

  for (int v = wid; v < N; v += nwaves) {
    int begin = offA[v], cnt = cntA[v];
    us4 hv = *(const us4*)(hvnew + (size_t)v * GG + kb);
    float da = bf2f(hv.x) * pn[0] + bf2f(hv.y) * pn[1] + bf2f(hv.z) * pn[2] + bf2f(hv.w) * pn[3];
#pragma unroll
    for (int o = 32; o; o >>= 1) da += __shfl_down(da, o);
    float alv = __shfl(da, 0) + pe2b0;

    float ss = 0.f;
    float a0 = 0.f, a1 = 0.f, a2 = 0.f, a3 = 0.f;
    int t = 0;
    for (; t + 4 <= cnt; t += 4) {
      int e[4], s[4];
#pragma unroll
      for (int u = 0; u < 4; ++u) {
        e[u] = __builtin_amdgcn_readfirstlane(elist[begin + t + u]);
        s[u] = __builtin_amdgcn_readfirstlane(srcA[e[u]]);
      }
      us4 g[4];
#pragma unroll
      for (int u = 0; u < 4; ++u) g[u] = *(const us4*)(xa + (size_t)s[u] * GG + kb);
      float h[4][4];
#pragma unroll
      for (int u = 0; u < 4; ++u) {
        h[u][0] = bf2f(g[u].x) + b[0];
        h[u][1] = bf2f(g[u].y) + b[1];
        h[u][2] = bf2f(g[u].z) + b[2];
        h[u][3] = bf2f(g[u].w) + b[3];
      }
#pragma unroll
      for (int jj = 0; jj < EE; ++jj) {
#pragma unroll
        for (int u = 0; u < 4; ++u) {
          float x = Xe[(size_t)e[u] * EE + jj];
          h[u][0] += x * pw[jj][0]; h[u][1] += x * pw[jj][1];
          h[u][2] += x * pw[jj][2]; h[u][3] += x * pw[jj][3];
        }
      }
      float bp[4];
#pragma unroll
      for (int u = 0; u < 4; ++u) {
#pragma unroll
        for (int j = 0; j < 4; ++j) h[u][j] = leakyf(h[u][j]);
        bp[u] = h[u][0] * p[0] + h[u][1] * p[1] + h[u][2] * p[2] + h[u][3] * p[3];
      }
#pragma unroll
      for (int o = 32; o; o >>= 1) {
#pragma unroll
        for (int u = 0; u < 4; ++u) bp[u] += __shfl_down(bp[u], o);
      }
#pragma unroll
      for (int u = 0; u < 4; ++u) {
        float w = __expf(fminf(leakyf(alv + __shfl(bp[u], 0)), 60.f));
        ss += w;
        a0 += w * h[u][0]; a1 += w * h[u][1]; a2 += w * h[u][2]; a3 += w * h[u][3];
      }
    }
    for (; t < cnt; ++t) {
      int e0 = __builtin_amdgcn_readfirstlane(elist[begin + t]);
      int s0 = __builtin_amdgcn_readfirstlane(srcA[e0]);
      us4 g0 = *(const us4*)(xa + (size_t)s0 * GG + kb);
      float h0 = bf2f(g0.x) + b[0], h1 = bf2f(g0.y) + b[1];
      float h2 = bf2f(g0.z) + b[2], h3 = bf2f(g0.w) + b[3];
#pragma unroll
      for (int jj = 0; jj < EE; ++jj) {
        float x = Xe[(size_t)e0 * EE + jj];
        h0 += x * pw[jj][0]; h1 += x * pw[jj][1];
        h2 += x * pw[jj][2]; h3 += x * pw[jj][3];
      }
      h0 = leakyf(h0); h1 = leakyf(h1); h2 = leakyf(h2); h3 = leakyf(h3);
      float bp = h0 * p[0] + h1 * p[1] + h2 * p[2] + h3 * p[3];
#pragma unroll
      for (int o = 32; o; o >>= 1) bp += __shfl_down(bp, o);
      float w = __expf(fminf(leakyf(alv + __shfl(bp, 0)), 60.f));
      ss += w;
      a0 += w * h0; a1 += w * h1; a2 += w * h2; a3 += w * h3;
    }
    float inv = (cnt > 0) ? rcp_f(ss) : 0.f;
    if (act) {
      us4 o4;
      o4.x = f2bf(a0 * inv); o4.y = f2bf(a1 * inv);
      o4.z = f2bf(a2 * inv); o4.w = f2bf(a3 * inv);
      *(us4*)(S + (size_t)v * GG + kb) = o4;
    }
    if (lane == 0) ssumOut[v] = (cnt > 0) ? ss : 0.f;
  }
}

// ---------------- layer-2 fused aggregation: persistent waves ----------------
__global__ __launch_bounds__(256) void l2_agg(
    const unsigned short* __restrict__ hvp, const float* __restrict__ gd,
    const float* __restrict__ gs, const float* __restrict__ lpeb,
    const int* __restrict__ srcA,
    const int* __restrict__ offA, const int* __restrict__ cntA, const int* __restrict__ elist,
    unsigned short* __restrict__ S2, int N, int nwaves)
{
  int wid = blockIdx.x * 4 + (threadIdx.x >> 6);
  int lane = threadIdx.x & 63;
  bool act = lane < 50;
  int kb = act ? 4 * lane : 0;
  float lpeb0 = lpeb[0];

  for (int v = wid; v < N; v += nwaves) {
    int begin = offA[v], cnt = cntA[v];
    float gdv = gd[v] + lpeb0;
    float ss = 0.f;
    float a0 = 0.f, a1 = 0.f, a2 = 0.f, a3 = 0.f;
    int t = 0;
    for (; t + 4 <= cnt; t += 4) {
      int e[4], s[4];
#pragma unroll
      for (int u = 0; u < 4; ++u) {
        e[u] = __builtin_amdgcn_readfirstlane(elist[begin + t + u]);
        s[u] = __builtin_amdgcn_readfirstlane(srcA[e[u]]);
      }
      us4 g0 = *(const us4*)(hvp + (size_t)s[0] * GG + kb);
      us4 g1 = *(const us4*)(hvp + (size_t)s[1] * GG + kb);
      us4 g2 = *(const us4*)(hvp + (size_t)s[2] * GG + kb);
      us4 g3 = *(const us4*)(hvp + (size_t)s[3] * GG + kb);
      float w0 = __expf(fminf(leakyf(gdv + gs[s[0]]), 60.f));
      float w1 = __expf(fminf(leakyf(gdv + gs[s[1]]), 60.f));
      float w2 = __expf(fminf(leakyf(gdv + gs[s[2]]), 60.f));
      float w3 = __expf(fminf(leakyf(gdv + gs[s[3]]), 60.f));
      ss += w0 + w1 + w2 + w3;
      a0 += w0 * bf2f(g0.x) + w1 * bf2f(g1.x) + w2 * bf2f(g2.x) + w3 * bf2f(g3.x);
      a1 += w0 * bf2f(g0.y) + w1 * bf2f(g1.y) + w2 * bf2f(g2.y) + w3 * bf2f(g3.y);
      a2 += w0 * bf2f(g0.z) + w1 * bf2f(g1.z) + w2 * bf2f(g2.z) + w3 * bf2f(g3.z);
      a3 += w0 * bf2f(g0.w) + w1 * bf2f(g1.w) + w2 * bf2f(g2.w) + w3 * bf2f(g3.w);
    }
    for (; t < cnt; ++t) {
      int e = __builtin_amdgcn_readfirstlane(elist[begin + t]);
      int s = __builtin_amdgcn_readfirstlane(srcA[e]);
      us4 g = *(const us4*)(hvp + (size_t)s * GG + kb);
      float w = __expf(fminf(leakyf(gdv + gs[s]), 60.f));
      ss += w;
      a0 += w * bf2f(g.x); a1 += w * bf2f(g.y);
      a2 += w * bf2f(g.z); a3 += w * bf2f(g.w);
    }
    float inv = (cnt > 0) ? rcp_f(ss) : 0.f;
    if (act) {
      us4 o4;
      o4.x = f2bf((cnt > 0) ? elu_fast(a0 * inv) : 0.f);
      o4.y = f2bf((cnt > 0) ? elu_fast(a1 * inv) : 0.f);
      o4.z = f2bf((cnt > 0) ? elu_fast(a2 * inv) : 0.f);
      o4.w = f2bf((cnt > 0) ? elu_fast(a3 * inv) : 0.f);
      *(us4*)(S2 + (size_t)v * GG + kb) = o4;
    }
  }
}

// ================= direct-from-L2 MFMA GEMM, packed-B =================
template <int NKC>
__global__ __launch_bounds__(256, 2) void mfma_gemm_d(
    const unsigned short* __restrict__ A, int strideA,
    const unsigned short* __restrict__ Wp,
    const float* __restrict__ bias, const float* __restrict__ rowmask,
    unsigned short* __restrict__ Cb, int Mr, int Nc, int act)
{
  int ncol = (Nc + 63) >> 6;
  int nrowt = (Mr + 127) >> 7;
  int per = 8 * ncol;
  int grp = blockIdx.x / per, rem = blockIdx.x % per;
  int rowt = grp * 8 + (rem & 7), colt = rem >> 3;
  if (rowt >= nrowt) return;
  int row0 = rowt * 128, col0 = colt * 64;
  int tid = threadIdx.x;
  int w = tid >> 6, lane = tid & 63, quad = lane >> 4, l15 = lane & 15;

  int rA0 = min(row0 + w * 32 + l15, Mr - 1);
  int rA1 = min(row0 + w * 32 + 16 + l15, Mr - 1);
  const unsigned short* pA0 = A + (size_t)rA0 * strideA + quad * 8;
  const unsigned short* pA1 = A + (size_t)rA1 * strideA + quad * 8;
  const unsigned short* pB[4];
#pragma unroll
  for (int c = 0; c < 4; ++c)
    pB[c] = Wp + ((size_t)(colt * 4 + c) * NKC) * 512 + lane * 8;

  f32x4 zero4 = {0.f, 0.f, 0.f, 0.f};
  f32x4 acc[2][4];
#pragma unroll
  for (int r = 0; r < 2; ++r)
#pragma unroll
    for (int c = 0; c < 4; ++c) acc[r][c] = zero4;

#pragma unroll
  for (int kc = 0; kc < NKC; ++kc) {
    bf16x8 a0 = *(const bf16x8*)(pA0 + kc * 32);
    bf16x8 a1 = *(const bf16x8*)(pA1 + kc * 32);
    bf16x8 b[4];
#pragma unroll
    for (int c = 0; c < 4; ++c) b[c] = *(const bf16x8*)(pB[c] + kc * 512);
#pragma unroll
    for (int c = 0; c < 4; ++c) {
      acc[0][c] = __builtin_amdgcn_mfma_f32_16x16x32_bf16(a0, b[c], acc[0][c], 0, 0, 0);
      acc[1][c] = __builtin_amdgcn_mfma_f32_16x16x32_bf16(a1, b[c], acc[1][c], 0, 0, 0);
    }
  }
#pragma unroll
  for (int r = 0; r < 2; ++r) {
#pragma unroll
    for (int c = 0; c < 4; ++c) {
      int col = col0 + c * 16 + l15;
      if (col >= Nc) continue;
#pragma unroll
      for (int i = 0; i < 4; ++i) {
        int row = row0 + w * 32 + r * 16 + quad * 4 + i;
        if (row >= Mr) continue;
        bool valid = (rowmask == nullptr) || (rowmask[row] > 0.f);
        float v = valid ? (acc[r][c][i] + (bias ? bias[col] : 0.f)) : 0.f;
        if (act == 1) v = leakyf(v);
        else if (act == 2) v = elu_fast(v);
        Cb[(size_t)row * Nc + col] = f2bf(v);
      }
    }
  }
}

// ================= direct-from-L2 fused MFMA GRU, packed-B =================
template <typename TI, typename TO>
__global__ __launch_bounds__(256, 2) void mfma_gru_d(
    const TI* __restrict__ X, const TI* __restrict__ H,
    const unsigned short* __restrict__ WIHp, const unsigned short* __restrict__ WHHp,
    const float* __restrict__ bih, const float* __restrict__ bhh,
    TO* __restrict__ Out, int R, int relu_out)
{
  int nrowt = (R + 127) >> 7;
  int grp = blockIdx.x / 56, rem = blockIdx.x % 56;
  int rowt = grp * 8 + (rem & 7), colt = rem >> 3;
  if (rowt >= nrowt) return;
  int row0 = rowt * 128, col0 = colt * 32;
  int tid = threadIdx.x;
  int w = tid >> 6, lane = tid & 63, quad = lane >> 4, l15 = lane & 15;

  int rA0 = min(row0 + w * 32 + l15, R - 1);
  int rA1 = min(row0 + w * 32 + 16 + l15, R - 1);
  const TI* pX0 = X + (size_t)rA0 * GG + quad * 8;
  const TI* pX1 = X + (size_t)rA1 * GG + quad * 8;
  const TI* pH0 = H + (size_t)rA0 * GG + quad * 8;
  const TI* pH1 = H + (size_t)rA1 * GG + quad * 8;
  const unsigned short* pBi[3][2];
  const unsigned short* pBh[3][2];
#pragma unroll
  for (int g = 0; g < 3; ++g)
#pragma unroll
    for (int c = 0; c < 2; ++c) {
      size_t tileoff = ((size_t)(g * 14 + colt * 2 + c) * 7) * 512 + lane * 8;
      pBi[g][c] = WIHp + tileoff;
      pBh[g][c] = WHHp + tileoff;
    }

  f32x4 zero4 = {0.f, 0.f, 0.f, 0.f};
  f32x4 acc[6][2][2];
#pragma unroll
  for (int g = 0; g < 6; ++g)
#pragma unroll
    for (int r = 0; r < 2; ++r)
#pragma unroll
      for (int c = 0; c < 2; ++c) acc[g][r][c] = zero4;

#pragma unroll
  for (int kc = 0; kc < 7; ++kc) {
    bf16x8 ax0 = afrag(pX0, kc * 32);
    bf16x8 ax1 = afrag(pX1, kc * 32);
    bf16x8 ah0 = afrag(pH0, kc * 32);
    bf16x8 ah1 = afrag(pH1, kc * 32);
#pragma unroll
    for (int g = 0; g < 3; ++g) {
      bf16x8 bi0 = *(const bf16x8*)(pBi[g][0] + kc * 512);
      bf16x8 bi1 = *(const bf16x8*)(pBi[g][1] + kc * 512);
      bf16x8 bh0 = *(const bf16x8*)(pBh[g][0] + kc * 512);
      bf16x8 bh1 = *(const bf16x8*)(pBh[g][1] + kc * 512);
      acc[g][0][0] = __builtin_amdgcn_mfma_f32_16x16x32_bf16(ax0, bi0, acc[g][0][0], 0, 0, 0);
      acc[g][0][1] = __builtin_amdgcn_mfma_f32_16x16x32_bf16(ax0, bi1, acc[g][0][1], 0, 0, 0);
      acc[g][1][0] = __builtin_amdgcn_mfma_f32_16x16x32_bf16(ax1, bi0, acc[g][1][0], 0, 0, 0);
      acc[g][1][1] = __builtin_amdgcn_mfma_f32_16x16x32_bf16(ax1, bi1, acc[g][1][1], 0, 0, 0);
      acc[g + 3][0][0] = __builtin_amdgcn_mfma_f32_16x16x32_bf16(ah0, bh0, acc[g + 3][0][0], 0, 0, 0);
      acc[g + 3][0][1] = __builtin_amdgcn_mfma_f32_16x16x32_bf16(ah0, bh1, acc[g + 3][0][1], 0, 0, 0);
      acc[g + 3][1][0] = __builtin_amdgcn_mfma_f32_16x16x32_bf16(ah1, bh0, acc[g + 3][1][0], 0, 0, 0);
      acc[g + 3][1][1] = __builtin_amdgcn_mfma_f32_16x16x32_bf16(ah1, bh1, acc[g + 3][1][1], 0, 0, 0);
    }
  }
#pragma unroll
  for (int r = 0; r < 2; ++r) {
#pragma unroll
    for (int c = 0; c < 2; ++c) {
      int col = col0 + c * 16 + l15;
      if (col >= GG) continue;
      float br = bih[col],       bhr = bhh[col];
      float bz = bih[200 + col], bhz = bhh[200 + col];
      float bn = bih[400 + col], bhn = bhh[400 + col];
#pragma unroll
      for (int i = 0; i < 4; ++i) {
        int row = row0 + w * 32 + r * 16 + quad * 4 + i;
        if (row >= R) continue;
        float rr = sigm_fast(acc[0][r][c][i] + br + acc[3][r][c][i] + bhr);
        float zz = sigm_fast(acc[1][r][c][i] + bz + acc[4][r][c][i] + bhz);
        float nn = tanh_fast(acc[2][r][c][i] + bn + rr * (acc[5][r][c][i] + bhn));
        float hval = ldv<TI>(H + (size_t)row * GG + col);
        float o = (1.f - zz) * nn + zz * hval;
        if (relu_out) o = fmaxf(o, 0.f);
        if constexpr (sizeof(TO) == 2) Out[(size_t)row * GG + col] = f2bf(o);
        else Out[(size_t)row * GG + col] = o;
      }
    }
  }
}

// ---------------- fp32 tiled GEMM (small readout shapes) ----------------
#define Bb 64
#define Bn 64
#define Bk 16
__global__ __launch_bounds__(256) void gemm_kernel(
    const float* __restrict__ A, const float* __restrict__ W,
    const float* __restrict__ bias, const float* __restrict__ rowmask,
    float* __restrict__ Cf, void* __restrict__ Oout, const int* __restrict__ oflag,
    int Mr, int Nc, int K, int act)
{
  __shared__ float As[Bk][Bb + 1];
  __shared__ float Ws[Bk][Bn];
  int row0 = blockIdx.x * Bb, col0 = blockIdx.y * Bn;
  int tid = threadIdx.x;
  int ty = tid >> 4, tx = tid & 15;
  float acc[4][4] = {};
  for (int k0 = 0; k0 < K; k0 += Bk) {
    for (int l = tid; l < Bb * Bk; l += 256) {
      int m = l >> 4, kk = l & 15;
      int r = row0 + m, k = k0 + kk;
      As[kk][m] = (r < Mr && k < K) ? A[(size_t)r * K + k] : 0.f;
    }
    for (int l = tid; l < Bk * Bn; l += 256) {
      int kk = l >> 6, nn = l & 63;
      int k = k0 + kk, c = col0 + nn;
      Ws[kk][nn] = (k < K && c < Nc) ? W[(size_t)k * Nc + c] : 0.f;
    }
    __syncthreads();
#pragma unroll
    for (int kk = 0; kk < Bk; ++kk) {
      float av[4], bv[4];
#pragma unroll
      for (int i = 0; i < 4; ++i) av[i] = As[kk][ty * 4 + i];
#pragma unroll
      for (int j = 0; j < 4; ++j) bv[j] = Ws[kk][tx * 4 + j];
#pragma unroll
      for (int i = 0; i < 4; ++i)
#pragma unroll
        for (int j = 0; j < 4; ++j) acc[i][j] += av[i] * bv[j];
    }
    __syncthreads();
  }
  int isbf = (oflag != nullptr) ? *oflag : 0;
#pragma unroll
  for (int i = 0; i < 4; ++i) {
    int r = row0 + ty * 4 + i;
    if (r >= Mr) continue;
    bool valid = (rowmask == nullptr) || (rowmask[r] > 0.f);
#pragma unroll
    for (int j = 0; j < 4; ++j) {
      int c = col0 + tx * 4 + j;
      if (c >= Nc) continue;
      float v = valid ? (acc[i][j] + (bias ? bias[c] : 0.f)) : 0.f;
      if (act == 1) v = leakyf(v);
      else if (act == 2) v = elu_fast(v);
      else if (act == 3) v = fmaxf(v, 0.f);
      size_t idx = (size_t)r * Nc + c;
      if (Oout) {
        if (isbf) ((__hip_bfloat16*)Oout)[idx] = __float2bfloat16(v);
        else      ((float*)Oout)[idx] = v;
      } else {
        Cf[idx] = v;
      }
    }
  }
}

// ---------------- per-node dot(s), bf16 input ----------------
__global__ __launch_bounds__(256) void node_dot2(
    const unsigned short* __restrict__ X, const float* __restrict__ w1,
    const float* __restrict__ w2,
    float* __restrict__ o1, float* __restrict__ o2, int N)
{
  int v = (blockIdx.x * 256 + threadIdx.x) >> 6;
  int lane = threadIdx.x & 63;
  if (v >= N) return;
  float d1 = 0.f, d2 = 0.f;
  for (int k = lane; k < GG; k += 64) {
    float x = bf2f(X[(size_t)v * GG + k]);
    d1 += x * w1[k];
    if (w2) d2 += x * w2[k];
  }
  for (int off = 32; off; off >>= 1) {
    d1 += __shfl_down(d1, off);
    if (w2) d2 += __shfl_down(d2, off);
  }
  if (lane == 0) { o1[v] = d1; if (w2) o2[v] = d2; }
}

__global__ __launch_bounds__(256) void graph_sum(
    const unsigned short* __restrict__ h, float* __restrict__ g)
{
  int b = blockIdx.x, k = threadIdx.x;
  if (k < GG) {
    float a = 0.f;
    for (int i = 0; i < 50; ++i) a += bf2f(h[((size_t)b * 50 + i) * GG + k]);
    g[(size_t)b * GG + k] = a;
  }
}

__global__ __launch_bounds__(256) void attn_kernel(
    const float* __restrict__ g, const unsigned short* __restrict__ h2,
    const float* __restrict__ w1, const float* __restrict__ dh,
    const float* __restrict__ rb, float* __restrict__ weighted)
{
  int b = blockIdx.x;
  __shared__ float red[256];
  __shared__ float zs[50];
  __shared__ float as_[50];
  __shared__ float dgs;
  int tid = threadIdx.x;
  float p = 0.f;
  if (tid < GG) p = fmaxf(g[(size_t)b * GG + tid], 0.f) * w1[tid];
  red[tid] = p;
  __syncthreads();
  for (int s = 128; s; s >>= 1) { if (tid < s) red[tid] += red[tid + s]; __syncthreads(); }
  if (tid == 0) dgs = red[0];
  __syncthreads();
  if (tid < 50) zs[tid] = leakyf(dgs + dh[b * 50 + tid] + rb[0]);
  __syncthreads();
  if (tid == 0) {
    float m = -1e30f;
    for (int i = 0; i < 50; ++i) m = fmaxf(m, zs[i]);
    float s = 0.f;
    for (int i = 0; i < 50; ++i) { float e = __expf(zs[i] - m); as_[i] = e; s += e; }
    float inv = 1.f / s;
    for (int i = 0; i < 50; ++i) as_[i] *= inv;
  }
  __syncthreads();
  if (tid < GG) {
    float a = 0.f;
    for (int i = 0; i < 50; ++i) a += as_[i] * bf2f(h2[((size_t)b * 50 + i) * GG + tid]);
    weighted[(size_t)b * GG + tid] = a;
  }
}

// ---------------- host ----------------
static inline int gemm_grid(int Mr, int Nc) {
  int nrow = (Mr + 127) / 128, ncol = (Nc + 63) / 64;
  return ((nrow + 7) / 8) * 8 * ncol;
}
static inline int gru_grid(int R) {
  int nrow = (R + 127) / 128;
  return ((nrow + 7) / 8) * 56;
}

extern "C" void kernel_launch(void* const* d_in, const int* in_sizes, int n_in,
                              void* d_out, int out_size, void* d_ws, size_t ws_size,
                              hipStream_t stream)
{
  (void)n_in; (void)out_size; (void)ws_size;
  const int N = NN, M = MM, B = BB, F = FF, G = GG, P = PP;
  const int PK7 = 14 * 7 * 512, PK2 = 14 * 2 * 512;
  float* ws = (float*)d_ws;
  size_t off = 0;
  auto alloc = [&](size_t n) { size_t o = off; off += (n + 63) & ~(size_t)63; return o; };

  size_t o_flag = alloc(16);
  size_t o_pn_w = alloc(F * G), o_pn_b = alloc(G);
  size_t o_pe1_w = alloc((F + EE) * G), o_pe1_b = alloc(G);
  size_t o_pe2_w = alloc(2 * G), o_pe2_b = alloc(1);
  size_t o_et_w = alloc(G * G), o_et_b = alloc(G);
  size_t o_g0_wih = alloc(G * 3 * G), o_g0_whh = alloc(G * 3 * G);
  size_t o_g0_bih = alloc(3 * G), o_g0_bhh = alloc(3 * G);
  size_t o_lpe_w = alloc(2 * G), o_lpe_b = alloc(1);
  size_t o_lpn_w = alloc(G * G), o_lpn_b = alloc(G);
  size_t o_g1_wih = alloc(G * 3 * G), o_g1_whh = alloc(G * 3 * G);
  size_t o_g1_bih = alloc(3 * G), o_g1_bhh = alloc(3 * G);
  size_t o_rl_w = alloc(2 * 2 * G), o_rl_b = alloc(2);
  size_t o_rp_w = alloc(2 * G * G), o_rp_b = alloc(2 * G);
  size_t o_rg_wih = alloc(2 * G * 3 * G), o_rg_whh = alloc(2 * G * 3 * G);
  size_t o_rg_bih = alloc(2 * 3 * G), o_rg_bhh = alloc(2 * 3 * G);
  size_t o_t_w = alloc(G * P), o_t_b = alloc(P);
  size_t o_Xnb = alloc((size_t)N * 40 / 2 + 64);
  size_t o_Xe = alloc((size_t)M * EE);
  size_t o_B1 = alloc((size_t)N * G);
  size_t o_B2 = alloc((size_t)N * G);
  size_t o_B3 = alloc((size_t)N * G);
  size_t o_ssum = alloc(N);
  size_t o_gd = alloc(N), o_gs = alloc(N), o_dh = alloc(N);
  size_t o_gv0 = alloc((size_t)B * G), o_gwt = alloc((size_t)B * G), o_grep = alloc((size_t)B * G + 64);
  size_t o_gv1 = alloc((size_t)B * G + 64), o_gv2 = alloc((size_t)B * G + 64);
  size_t o_etP  = alloc(PK7 / 2 + 64), o_lpnP = alloc(PK7 / 2 + 64);
  size_t o_g0ihP = alloc(3 * PK7 / 2 + 64), o_g0hhP = alloc(3 * PK7 / 2 + 64);
  size_t o_g1ihP = alloc(3 * PK7 / 2 + 64), o_g1hhP = alloc(3 * PK7 / 2 + 64);
  size_t o_rg0ihP = alloc(3 * PK7 / 2 + 64), o_rg0hhP = alloc(3 * PK7 / 2 + 64);
  size_t o_rg1ihP = alloc(3 * PK7 / 2 + 64), o_rg1hhP = alloc(3 * PK7 / 2 + 64);
  size_t o_pnP = alloc(PK2 / 2 + 64), o_pe1P = alloc(PK2 / 2 + 64);
  size_t o_cnt = alloc(N), o_off = alloc(N), o_cur = alloc(N);
  size_t o_elist = alloc(M), o_bsum = alloc(64), o_incl = alloc(N);

  int* flag = (int*)(ws + o_flag);
  int* cntA = (int*)(ws + o_cnt);
  int* offA = (int*)(ws + o_off);
  int* curA = (int*)(ws + o_cur);
  int* elist = (int*)(ws + o_elist);
  int* bsum = (int*)(ws + o_bsum);
  int* incl = (int*)(ws + o_incl);
  unsigned short* Xnb = (unsigned short*)(ws + o_Xnb);
  unsigned short* B1b = (unsigned short*)(ws + o_B1);
  unsigned short* B2b = (unsigned short*)(ws + o_B2);
  unsigned short* B3b = (unsigned short*)(ws + o_B3);

  CvtJobs32 jobs;
  int ji = 0;
  auto push = [&](int idx, size_t dsto) {
    jobs.j[ji].s = d_in[idx];
    jobs.j[ji].d = ws + dsto;
    jobs.j[ji].n = in_sizes[idx];
    jobs.j[ji].pad = 0;
    ++ji;
  };
  push(1, o_Xe);
  push(2, o_pn_w);  push(3, o_pn_b);
  push(4, o_pe1_w); push(5, o_pe1_b);
  push(6, o_pe2_w); push(7, o_pe2_b);
  push(8, o_et_w);  push(9, o_et_b);
  push(10, o_g0_wih); push(11, o_g0_whh); push(12, o_g0_bih); push(13, o_g0_bhh);
  push(14, o_lpe_w);  push(15, o_lpe_b);
  push(16, o_lpn_w);  push(17, o_lpn_b);
  push(18, o_g1_wih); push(19, o_g1_whh); push(20, o_g1_bih); push(21, o_g1_bhh);
  push(22, o_rl_w);   push(23, o_rl_b);
  push(24, o_rp_w);   push(25, o_rp_b);
  push(26, o_rg_wih); push(27, o_rg_whh); push(28, o_rg_bih); push(29, o_rg_bhh);
  push(30, o_t_w);    push(31, o_t_b);

  const int* src = (const int*)d_in[32];
  const int* dst = (const int*)d_in[33];

  dim3 blk(256);
  detect_dtype<<<dim3(1), blk, 0, stream>>>((const unsigned int*)d_in[0], flag);
  cvt_any<<<dim3(512, 31), blk, 0, stream>>>(jobs, flag);
  cvt_xn<<<dim3((N * 40 + 255) / 256), blk, 0, stream>>>(d_in[0], Xnb, flag, N);

  // ---- CSR build (by dst) ----
  hipMemsetAsync(cntA, 0, (size_t)N * 4, stream);
  hist_kernel<<<dim3((M + 255) / 256), blk, 0, stream>>>(dst, cntA, M);
  int nscb = (N + SCHUNK - 1) / SCHUNK;
  scan1_kernel<<<dim3(nscb), blk, 0, stream>>>(cntA, incl, bsum, N);
  scan2_kernel<<<dim3(1), dim3(64), 0, stream>>>(bsum, nscb);
  scan3_kernel<<<dim3((N + 255) / 256), blk, 0, stream>>>(incl, cntA, bsum, offA, curA, N);
  fill_kernel<<<dim3((M + 255) / 256), blk, 0, stream>>>(dst, curA, elist, M);

  // ---- weight packing (fragment-major) ----
  PJobs28 pj;
  int pi = 0;
  auto ppush = [&](size_t srcO, size_t dstOshorts_base, int slot_shorts, int K, int Ns, int coff, int nkc) {
    pj.j[pi].s = ws + srcO;
    pj.j[pi].d = (unsigned short*)(ws + dstOshorts_base) + slot_shorts;
    pj.j[pi].K = K; pj.j[pi].Ns = Ns; pj.j[pi].coff = coff; pj.j[pi].nkc = nkc;
    ++pi;
  };
  ppush(o_et_w,  o_etP,  0, G, G, 0, 7);
  ppush(o_lpn_w, o_lpnP, 0, G, G, 0, 7);
  for (int g = 0; g < 3; ++g) {
    ppush(o_g0_wih, o_g0ihP, g * PK7, G, 3 * G, g * G, 7);
    ppush(o_g0_whh, o_g0hhP, g * PK7, G, 3 * G, g * G, 7);
    ppush(o_g1_wih, o_g1ihP, g * PK7, G, 3 * G, g * G, 7);
    ppush(o_g1_whh, o_g1hhP, g * PK7, G, 3 * G, g * G, 7);
    ppush(o_rg_wih, o_rg0ihP, g * PK7, G, 3 * G, g * G, 7);
    ppush(o_rg_whh, o_rg0hhP, g * PK7, G, 3 * G, g * G, 7);
    ppush(o_rg_wih + (size_t)G * 3 * G, o_rg1ihP, g * PK7, G, 3 * G, g * G, 7);
    ppush(o_rg_whh + (size_t)G * 3 * G, o_rg1hhP, g * PK7, G, 3 * G, g * G, 7);
  }
  ppush(o_pn_w,  o_pnP,  0, F, G, 0, 2);
  ppush(o_pe1_w, o_pe1P, 0, F, G, 0, 2);
  pack_bf16<<<dim3(64, 28), blk, 0, stream>>>(pj);

  int gg = gemm_grid(N, G);
  mfma_gemm_d<2><<<dim3(gg), blk, 0, stream>>>(
      Xnb, 40, (const unsigned short*)(ws + o_pnP),
      ws + o_pn_b, nullptr, B1b, N, G, 1);
  mfma_gemm_d<2><<<dim3(gg), blk, 0, stream>>>(
      Xnb, 40, (const unsigned short*)(ws + o_pe1P),
      nullptr, nullptr, B2b, N, G, 0);
  // persistent-wave aggregation: 2048 blocks x 4 waves
  const int AGG_BLOCKS = 2048, NW = AGG_BLOCKS * 4;
  l1_agg<<<dim3(AGG_BLOCKS), blk, 0, stream>>>(ws + o_Xe, B2b, B1b,
                                           ws + o_pe1_w + (size_t)F * G, ws + o_pe1_b,
                                           ws + o_pe2_w, ws + o_pe2_w + G, ws + o_pe2_b,
                                           src, offA, cntA, elist,
                                           B3b, ws + o_ssum, N, NW);
  mfma_gemm_d<7><<<dim3(gg), blk, 0, stream>>>(
      B3b, G, (const unsigned short*)(ws + o_etP),
      ws + o_et_b, ws + o_ssum, B2b, N, G, 2);
  mfma_gru_d<unsigned short, unsigned short><<<dim3(gru_grid(N)), blk, 0, stream>>>(
      B2b, B1b,
      (const unsigned short*)(ws + o_g0ihP), (const unsigned short*)(ws + o_g0hhP),
      ws + o_g0_bih, ws + o_g0_bhh, B3b, N, 1);

  // ---- layer 2 ----
  dim3 gWave((N + 3) / 4);
  node_dot2<<<gWave, blk, 0, stream>>>(B3b, ws + o_lpe_w, ws + o_lpe_w + G,
                                       ws + o_gd, ws + o_gs, N);
  mfma_gemm_d<7><<<dim3(gg), blk, 0, stream>>>(
      B3b, G, (const unsigned short*)(ws + o_lpnP),
      ws + o_lpn_b, nullptr, B1b, N, G, 0);
  l2_agg<<<dim3(AGG_BLOCKS), blk, 0, stream>>>(B1b, ws + o_gd, ws + o_gs, ws + o_lpe_b,
                                           src, offA, cntA, elist, B2b, N, NW);
  mfma_gru_d<unsigned short, unsigned short><<<dim3(gru_grid(N)), blk, 0, stream>>>(
      B2b, B3b,
      (const unsigned short*)(ws + o_g1ihP), (const unsigned short*)(ws + o_g1hhP),
      ws + o_g1_bih, ws + o_g1_bhh, B1b, N, 1);

  // ---- readout ----
  graph_sum<<<dim3(B), blk, 0, stream>>>(B1b, ws + o_gv0);
  dim3 gBG((B + Bb - 1) / Bb, (G + Bn - 1) / Bn);
  size_t gcur = o_gv0, gnext = o_gv1;
  for (int t = 0; t < 2; ++t) {
    node_dot2<<<gWave, blk, 0, stream>>>(B1b, ws + o_rl_w + t * 2 * G + G,
                                         nullptr, ws + o_dh, nullptr, N);
    attn_kernel<<<dim3(B), blk, 0, stream>>>(ws + gcur, B1b, ws + o_rl_w + t * 2 * G,
                                             ws + o_dh, ws + o_rl_b + t, ws + o_gwt);
    gemm_kernel<<<gBG, blk, 0, stream>>>(ws + o_gwt, ws + o_rp_w + (size_t)t * G * G,
                                         ws + o_rp_b + t * G, nullptr,
                                         ws + o_grep, nullptr, nullptr, B, G, G, 2);
    mfma_gru_d<float, float><<<dim3(gru_grid(B)), blk, 0, stream>>>(
        ws + o_grep, ws + gcur,
        (const unsigned short*)(ws + (t == 0 ? o_rg0ihP : o_rg1ihP)),
        (const unsigned short*)(ws + (t == 0 ? o_rg0hhP : o_rg1hhP)),
        ws + o_rg_bih + t * 3 * G, ws + o_rg_bhh + t * 3 * G,
        ws + gnext, B, 0);
    gcur = gnext;
    gnext = o_gv2;
  }
  dim3 gOut((B + Bb - 1) / Bb, (P + Bn - 1) / Bn);
  gemm_kernel<<<gOut, blk, 0, stream>>>(ws + gcur, ws + o_t_w, ws + o_t_b, nullptr,
                                        nullptr, d_out, flag, B, P, G, 0);
}

// Round 14
// 796.714 us; speedup vs baseline: 1.0393x; 1.0322x over previous
//
#include <hip/hip_runtime.h>
#include <hip/hip_bf16.h>

// ---------------- constants ----------------
#define NN 50000
#define MM 400000
#define BB 1000
#define FF 39
#define EE 11
#define GG 200
#define PP 128

typedef __attribute__((ext_vector_type(8))) short bf16x8;
typedef __attribute__((ext_vector_type(4))) float f32x4;
struct us4 { unsigned short x, y, z, w; };

// ---------------- helpers ----------------
__device__ __forceinline__ float bf2f(unsigned short u) {
  return __uint_as_float(((unsigned int)u) << 16);
}
__device__ __forceinline__ unsigned short f2bf(float x) {
  union { __hip_bfloat16 b; unsigned short u; } v;
  v.b = __float2bfloat16(x);
  return v.u;
}
__device__ __forceinline__ float rcp_f(float x) { return __builtin_amdgcn_rcpf(x); }
__device__ __forceinline__ float leakyf(float x) { return x > 0.f ? x : 0.01f * x; }
__device__ __forceinline__ float elu_fast(float x)  { return x > 0.f ? x : __expf(x) - 1.f; }
__device__ __forceinline__ float sigm_fast(float x) { return rcp_f(1.f + __expf(-x)); }
__device__ __forceinline__ float tanh_fast(float x) { return 1.f - 2.f * rcp_f(1.f + __expf(2.f * x)); }
template <typename T> __device__ __forceinline__ float ldv(const T* p);
template <> __device__ __forceinline__ float ldv<float>(const float* p) { return *p; }
template <> __device__ __forceinline__ float ldv<unsigned short>(const unsigned short* p) { return bf2f(*p); }

template <typename T>
__device__ __forceinline__ bf16x8 afrag(const T* base, size_t off) {
  if constexpr (sizeof(T) == 2) {
    return *(const bf16x8*)(base + off);
  } else {
    float4 f0 = *(const float4*)(base + off);
    float4 f1 = *(const float4*)(base + off + 4);
    short t[8];
    t[0] = (short)f2bf(f0.x); t[1] = (short)f2bf(f0.y);
    t[2] = (short)f2bf(f0.z); t[3] = (short)f2bf(f0.w);
    t[4] = (short)f2bf(f1.x); t[5] = (short)f2bf(f1.y);
    t[6] = (short)f2bf(f1.z); t[7] = (short)f2bf(f1.w);
    return *(bf16x8*)t;
  }
}

// ---------------- runtime dtype detection ----------------
__global__ __launch_bounds__(256) void detect_dtype(const unsigned int* __restrict__ w,
                                                    int* __restrict__ flag) {
  __shared__ int cnt[256];
  int c = 0;
  for (int i = threadIdx.x; i < 2048; i += 256) {
    unsigned int e = (w[i] >> 8) & 0x7F;
    c += (e >= 60 && e <= 64) ? 1 : 0;
  }
  cnt[threadIdx.x] = c;
  __syncthreads();
  for (int s = 128; s; s >>= 1) {
    if (threadIdx.x < s) cnt[threadIdx.x] += cnt[threadIdx.x + s];
    __syncthreads();
  }
  if (threadIdx.x == 0) *flag = (cnt[0] >= 1024) ? 1 : 0;
}

// ---------------- batched conversion to f32 ----------------
struct CvtJob { const void* s; float* d; int n; int pad; };
struct CvtJobs32 { CvtJob j[32]; };

__global__ __launch_bounds__(256) void cvt_any(CvtJobs32 jobs, const int* __restrict__ flag) {
  CvtJob job = jobs.j[blockIdx.y];
  int isbf = *flag;
  if (isbf) {
    const unsigned short* s = (const unsigned short*)job.s;
    for (int i = blockIdx.x * 256 + threadIdx.x; i < job.n; i += gridDim.x * 256)
      job.d[i] = bf2f(s[i]);
  } else {
    const float* s = (const float*)job.s;
    for (int i = blockIdx.x * 256 + threadIdx.x; i < job.n; i += gridDim.x * 256)
      job.d[i] = s[i];
  }
}

// Xn -> bf16 padded [N][40]
__global__ __launch_bounds__(256) void cvt_xn(const void* __restrict__ src,
                                              unsigned short* __restrict__ dstb,
                                              const int* __restrict__ flag, int N) {
  int isbf = *flag;
  int total = N * 40;
  for (int i = blockIdx.x * 256 + threadIdx.x; i < total; i += gridDim.x * 256) {
    int n = i / 40, k = i - n * 40;
    unsigned short v = 0;
    if (k < FF) {
      if (isbf) v = ((const unsigned short*)src)[n * FF + k];
      else      v = f2bf(((const float*)src)[n * FF + k]);
    }
    dstb[i] = v;
  }
}

// ---------------- fragment-major weight pack ----------------
struct PJob { const float* s; unsigned short* d; int K; int Ns; int coff; int nkc; };
struct PJobs28 { PJob j[28]; };

__global__ __launch_bounds__(256) void pack_bf16(PJobs28 jobs) {
  PJob job = jobs.j[blockIdx.y];
  int per = job.nkc * 512;
  int total = 14 * per;
  for (int idx = blockIdx.x * 256 + threadIdx.x; idx < total; idx += gridDim.x * 256) {
    int ct = idx / per, r = idx - ct * per;
    int kc = r >> 9, e = r & 511;
    int lane = e >> 3, j = e & 7;
    int n = ct * 16 + (lane & 15);
    int k = kc * 32 + (lane >> 4) * 8 + j;
    job.d[idx] = (k < job.K && n < GG)
        ? f2bf(job.s[(size_t)k * job.Ns + job.coff + n]) : (unsigned short)0;
  }
}

// ---------------- CSR build ----------------
__global__ __launch_bounds__(256) void hist_kernel(const int* __restrict__ dst,
                                                   int* __restrict__ cnt, int M) {
  int e = blockIdx.x * 256 + threadIdx.x;
  if (e < M) atomicAdd(&cnt[dst[e]], 1);
}

#define SCHUNK 2048
__global__ __launch_bounds__(256) void scan1_kernel(const int* __restrict__ cnt,
                                                    int* __restrict__ incl,
                                                    int* __restrict__ bsum, int n) {
  __shared__ int lds[256];
  int b = blockIdx.x, tid = threadIdx.x;
  int base = b * SCHUNK + tid * 8;
  int v[8], s = 0;
#pragma unroll
  for (int j = 0; j < 8; ++j) { int i = base + j; v[j] = (i < n) ? cnt[i] : 0; s += v[j]; }
  lds[tid] = s;
  __syncthreads();
  for (int o = 1; o < 256; o <<= 1) {
    int t = (tid >= o) ? lds[tid - o] : 0;
    __syncthreads();
    lds[tid] += t;
    __syncthreads();
  }
  int run = lds[tid] - s;
#pragma unroll
  for (int j = 0; j < 8; ++j) {
    run += v[j];
    int i = base + j;
    if (i < n) incl[i] = run;
  }
  if (tid == 255) bsum[b] = lds[255];
}

__global__ void scan2_kernel(int* __restrict__ bsum, int nb) {
  if (threadIdx.x == 0 && blockIdx.x == 0) {
    int run = 0;
    for (int i = 0; i < nb; ++i) { int t = bsum[i]; bsum[i] = run; run += t; }
  }
}

__global__ __launch_bounds__(256) void scan3_kernel(const int* __restrict__ incl,
                                                    const int* __restrict__ cnt,
                                                    const int* __restrict__ bsum,
                                                    int* __restrict__ offA,
                                                    int* __restrict__ cur, int n) {
  int i = blockIdx.x * 256 + threadIdx.x;
  if (i >= n) return;
  int o = incl[i] - cnt[i] + bsum[i / SCHUNK];
  offA[i] = o;
  cur[i] = o;
}

__global__ __launch_bounds__(256) void fill_kernel(const int* __restrict__ dst,
                                                   int* __restrict__ cur,
                                                   int* __restrict__ elist, int M) {
  int e = blockIdx.x * 256 + threadIdx.x;
  if (e >= M) return;
  int pos = atomicAdd(&cur[dst[e]], 1);
  elist[pos] = e;
}

// ---------------- layer-1 fused aggregation: one wave per block (R11 config) ----------------
__global__ __launch_bounds__(64) void l1_agg(
    const float* __restrict__ Xe, const unsigned short* __restrict__ xa,
    const unsigned short* __restrict__ hvnew,
    const float* __restrict__ pe1w_e, const float* __restrict__ pe1b,
    const float* __restrict__ pe2w_n, const float* __restrict__ pe2w_e,
    const float* __restrict__ pe2b, const int* __restrict__ srcA,
    const int* __restrict__ offA, const int* __restrict__ cntA, const int* __restrict__ elist,
    unsigned short* __restrict__ S, float* __restrict__ ssumOut, int N)
{
  int v = blockIdx.x;
  int lane = threadIdx.x;
  if (v >= N) return;
  int begin = offA[v], cnt = cntA[v];
  bool act = lane < 50;
  int kb = act ? 4 * lane : 0;
  float b[4], p[4], pn[4];
  float pw[EE][4];
#pragma unroll
  for (int j = 0; j < 4; ++j) {
    b[j]  = pe1b[kb + j];
    p[j]  = act ? pe2w_e[kb + j] : 0.f;
    pn[j] = act ? pe2w_n[kb + j] : 0.f;
  }
#pragma unroll
  for (int jj = 0; jj < EE; ++jj)
#pragma unroll
    for (int j = 0; j < 4; ++j) pw[jj][j] = pe1w_e[jj * GG + kb + j];

  us4 hv = *(const us4*)(hvnew + (size_t)v * GG + kb);
  float da = bf2f(hv.x) * pn[0] + bf2f(hv.y) * pn[1] + bf2f(hv.z) * pn[2] + bf2f(hv.w) * pn[3];
#pragma unroll
  for (int o = 32; o; o >>= 1) da += __shfl_down(da, o);
  float alv = __shfl(da, 0) + pe2b[0];

  float ss = 0.f;
  float a0 = 0.f, a1 = 0.f, a2 = 0.f, a3 = 0.f;
  int t = 0;
  for (; t + 4 <= cnt; t += 4) {
    int e[4], s[4];
#pragma unroll
    for (int u = 0; u < 4; ++u) {
      e[u] = __builtin_amdgcn_readfirstlane(elist[begin + t + u]);
      s[u] = __builtin_amdgcn_readfirstlane(srcA[e[u]]);
    }
    us4 g[4];
#pragma unroll
    for (int u = 0; u < 4; ++u) g[u] = *(const us4*)(xa + (size_t)s[u] * GG + kb);
    float h[4][4];
#pragma unroll
    for (int u = 0; u < 4; ++u) {
      h[u][0] = bf2f(g[u].x) + b[0];
      h[u][1] = bf2f(g[u].y) + b[1];
      h[u][2] = bf2f(g[u].z) + b[2];
      h[u][3] = bf2f(g[u].w) + b[3];
    }
#pragma unroll
    for (int jj = 0; jj < EE; ++jj) {
#pragma unroll
      for (int u = 0; u < 4; ++u) {
        float x = Xe[(size_t)e[u] * EE + jj];
        h[u][0] += x * pw[jj][0]; h[u][1] += x * pw[jj][1];
        h[u][2] += x * pw[jj][2]; h[u][3] += x * pw[jj][3];
      }
    }
    float bp[4];
#pragma unroll
    for (int u = 0; u < 4; ++u) {
#pragma unroll
      for (int j = 0; j < 4; ++j) h[u][j] = leakyf(h[u][j]);
      bp[u] = h[u][0] * p[0] + h[u][1] * p[1] + h[u][2] * p[2] + h[u][3] * p[3];
    }
#pragma unroll
    for (int o = 32; o; o >>= 1) {
#pragma unroll
      for (int u = 0; u < 4; ++u) bp[u] += __shfl_down(bp[u], o);
    }
#pragma unroll
    for (int u = 0; u < 4; ++u) {
      float w = __expf(fminf(leakyf(alv + __shfl(bp[u], 0)), 60.f));
      ss += w;
      a0 += w * h[u][0]; a1 += w * h[u][1]; a2 += w * h[u][2]; a3 += w * h[u][3];
    }
  }
  for (; t < cnt; ++t) {
    int e0 = __builtin_amdgcn_readfirstlane(elist[begin + t]);
    int s0 = __builtin_amdgcn_readfirstlane(srcA[e0]);
    us4 g0 = *(const us4*)(xa + (size_t)s0 * GG + kb);
    float h0 = bf2f(g0.x) + b[0], h1 = bf2f(g0.y) + b[1];
    float h2 = bf2f(g0.z) + b[2], h3 = bf2f(g0.w) + b[3];
#pragma unroll
    for (int jj = 0; jj < EE; ++jj) {
      float x = Xe[(size_t)e0 * EE + jj];
      h0 += x * pw[jj][0]; h1 += x * pw[jj][1];
      h2 += x * pw[jj][2]; h3 += x * pw[jj][3];
    }
    h0 = leakyf(h0); h1 = leakyf(h1); h2 = leakyf(h2); h3 = leakyf(h3);
    float bp = h0 * p[0] + h1 * p[1] + h2 * p[2] + h3 * p[3];
#pragma unroll
    for (int o = 32; o; o >>= 1) bp += __shfl_down(bp, o);
    float w = __expf(fminf(leakyf(alv + __shfl(bp, 0)), 60.f));
    ss += w;
    a0 += w * h0; a1 += w * h1; a2 += w * h2; a3 += w * h3;
  }
  float inv = (cnt > 0) ? rcp_f(ss) : 0.f;
  if (act) {
    us4 o4;
    o4.x = f2bf(a0 * inv); o4.y = f2bf(a1 * inv);
    o4.z = f2bf(a2 * inv); o4.w = f2bf(a3 * inv);
    *(us4*)(S + (size_t)v * GG + kb) = o4;
  }
  if (lane == 0) ssumOut[v] = (cnt > 0) ? ss : 0.f;
}

// ---------------- layer-2 fused aggregation: one wave per block (R11 config) ----------------
__global__ __launch_bounds__(64) void l2_agg(
    const unsigned short* __restrict__ hvp, const float* __restrict__ gd,
    const float* __restrict__ gs, const float* __restrict__ lpeb,
    const int* __restrict__ srcA,
    const int* __restrict__ offA, const int* __restrict__ cntA, const int* __restrict__ elist,
    unsigned short* __restrict__ S2, int N)
{
  int v = blockIdx.x;
  int lane = threadIdx.x;
  if (v >= N) return;
  int begin = offA[v], cnt = cntA[v];
  bool act = lane < 50;
  int kb = act ? 4 * lane : 0;
  float gdv = gd[v] + lpeb[0];
  float ss = 0.f;
  float a0 = 0.f, a1 = 0.f, a2 = 0.f, a3 = 0.f;
  int t = 0;
  for (; t + 4 <= cnt; t += 4) {
    int e[4], s[4];
#pragma unroll
    for (int u = 0; u < 4; ++u) {
      e[u] = __builtin_amdgcn_readfirstlane(elist[begin + t + u]);
      s[u] = __builtin_amdgcn_readfirstlane(srcA[e[u]]);
    }
    us4 g0 = *(const us4*)(hvp + (size_t)s[0] * GG + kb);
    us4 g1 = *(const us4*)(hvp + (size_t)s[1] * GG + kb);
    us4 g2 = *(const us4*)(hvp + (size_t)s[2] * GG + kb);
    us4 g3 = *(const us4*)(hvp + (size_t)s[3] * GG + kb);
    float w0 = __expf(fminf(leakyf(gdv + gs[s[0]]), 60.f));
    float w1 = __expf(fminf(leakyf(gdv + gs[s[1]]), 60.f));
    float w2 = __expf(fminf(leakyf(gdv + gs[s[2]]), 60.f));
    float w3 = __expf(fminf(leakyf(gdv + gs[s[3]]), 60.f));
    ss += w0 + w1 + w2 + w3;
    a0 += w0 * bf2f(g0.x) + w1 * bf2f(g1.x) + w2 * bf2f(g2.x) + w3 * bf2f(g3.x);
    a1 += w0 * bf2f(g0.y) + w1 * bf2f(g1.y) + w2 * bf2f(g2.y) + w3 * bf2f(g3.y);
    a2 += w0 * bf2f(g0.z) + w1 * bf2f(g1.z) + w2 * bf2f(g2.z) + w3 * bf2f(g3.z);
    a3 += w0 * bf2f(g0.w) + w1 * bf2f(g1.w) + w2 * bf2f(g2.w) + w3 * bf2f(g3.w);
  }
  for (; t < cnt; ++t) {
    int e = __builtin_amdgcn_readfirstlane(elist[begin + t]);
    int s = __builtin_amdgcn_readfirstlane(srcA[e]);
    us4 g = *(const us4*)(hvp + (size_t)s * GG + kb);
    float w = __expf(fminf(leakyf(gdv + gs[s]), 60.f));
    ss += w;
    a0 += w * bf2f(g.x); a1 += w * bf2f(g.y);
    a2 += w * bf2f(g.z); a3 += w * bf2f(g.w);
  }
  float inv = (cnt > 0) ? rcp_f(ss) : 0.f;
  if (act) {
    us4 o4;
    o4.x = f2bf((cnt > 0) ? elu_fast(a0 * inv) : 0.f);
    o4.y = f2bf((cnt > 0) ? elu_fast(a1 * inv) : 0.f);
    o4.z = f2bf((cnt > 0) ? elu_fast(a2 * inv) : 0.f);
    o4.w = f2bf((cnt > 0) ? elu_fast(a3 * inv) : 0.f);
    *(us4*)(S2 + (size_t)v * GG + kb) = o4;
  }
}

// ================= direct-from-L2 MFMA GEMM, packed-B =================
template <int NKC>
__global__ __launch_bounds__(256, 2) void mfma_gemm_d(
    const unsigned short* __restrict__ A, int strideA,
    const unsigned short* __restrict__ Wp,
    const float* __restrict__ bias, const float* __restrict__ rowmask,
    unsigned short* __restrict__ Cb, int Mr, int Nc, int act)
{
  int ncol = (Nc + 63) >> 6;
  int nrowt = (Mr + 127) >> 7;
  int per = 8 * ncol;
  int grp = blockIdx.x / per, rem = blockIdx.x % per;
  int rowt = grp * 8 + (rem & 7), colt = rem >> 3;
  if (rowt >= nrowt) return;
  int row0 = rowt * 128, col0 = colt * 64;
  int tid = threadIdx.x;
  int w = tid >> 6, lane = tid & 63, quad = lane >> 4, l15 = lane & 15;

  int rA0 = min(row0 + w * 32 + l15, Mr - 1);
  int rA1 = min(row0 + w * 32 + 16 + l15, Mr - 1);
  const unsigned short* pA0 = A + (size_t)rA0 * strideA + quad * 8;
  const unsigned short* pA1 = A + (size_t)rA1 * strideA + quad * 8;
  const unsigned short* pB[4];
#pragma unroll
  for (int c = 0; c < 4; ++c)
    pB[c] = Wp + ((size_t)(colt * 4 + c) * NKC) * 512 + lane * 8;

  f32x4 zero4 = {0.f, 0.f, 0.f, 0.f};
  f32x4 acc[2][4];
#pragma unroll
  for (int r = 0; r < 2; ++r)
#pragma unroll
    for (int c = 0; c < 4; ++c) acc[r][c] = zero4;

#pragma unroll
  for (int kc = 0; kc < NKC; ++kc) {
    bf16x8 a0 = *(const bf16x8*)(pA0 + kc * 32);
    bf16x8 a1 = *(const bf16x8*)(pA1 + kc * 32);
    bf16x8 b[4];
#pragma unroll
    for (int c = 0; c < 4; ++c) b[c] = *(const bf16x8*)(pB[c] + kc * 512);
#pragma unroll
    for (int c = 0; c < 4; ++c) {
      acc[0][c] = __builtin_amdgcn_mfma_f32_16x16x32_bf16(a0, b[c], acc[0][c], 0, 0, 0);
      acc[1][c] = __builtin_amdgcn_mfma_f32_16x16x32_bf16(a1, b[c], acc[1][c], 0, 0, 0);
    }
  }
#pragma unroll
  for (int r = 0; r < 2; ++r) {
#pragma unroll
    for (int c = 0; c < 4; ++c) {
      int col = col0 + c * 16 + l15;
      if (col >= Nc) continue;
#pragma unroll
      for (int i = 0; i < 4; ++i) {
        int row = row0 + w * 32 + r * 16 + quad * 4 + i;
        if (row >= Mr) continue;
        bool valid = (rowmask == nullptr) || (rowmask[row] > 0.f);
        float v = valid ? (acc[r][c][i] + (bias ? bias[col] : 0.f)) : 0.f;
        if (act == 1) v = leakyf(v);
        else if (act == 2) v = elu_fast(v);
        Cb[(size_t)row * Nc + col] = f2bf(v);
      }
    }
  }
}

// ================= direct-from-L2 fused MFMA GRU, packed-B =================
template <typename TI, typename TO>
__global__ __launch_bounds__(256, 2) void mfma_gru_d(
    const TI* __restrict__ X, const TI* __restrict__ H,
    const unsigned short* __restrict__ WIHp, const unsigned short* __restrict__ WHHp,
    const float* __restrict__ bih, const float* __restrict__ bhh,
    TO* __restrict__ Out, int R, int relu_out)
{
  int nrowt = (R + 127) >> 7;
  int grp = blockIdx.x / 56, rem = blockIdx.x % 56;
  int rowt = grp * 8 + (rem & 7), colt = rem >> 3;
  if (rowt >= nrowt) return;
  int row0 = rowt * 128, col0 = colt * 32;
  int tid = threadIdx.x;
  int w = tid >> 6, lane = tid & 63, quad = lane >> 4, l15 = lane & 15;

  int rA0 = min(row0 + w * 32 + l15, R - 1);
  int rA1 = min(row0 + w * 32 + 16 + l15, R - 1);
  const TI* pX0 = X + (size_t)rA0 * GG + quad * 8;
  const TI* pX1 = X + (size_t)rA1 * GG + quad * 8;
  const TI* pH0 = H + (size_t)rA0 * GG + quad * 8;
  const TI* pH1 = H + (size_t)rA1 * GG + quad * 8;
  const unsigned short* pBi[3][2];
  const unsigned short* pBh[3][2];
#pragma unroll
  for (int g = 0; g < 3; ++g)
#pragma unroll
    for (int c = 0; c < 2; ++c) {
      size_t tileoff = ((size_t)(g * 14 + colt * 2 + c) * 7) * 512 + lane * 8;
      pBi[g][c] = WIHp + tileoff;
      pBh[g][c] = WHHp + tileoff;
    }

  f32x4 zero4 = {0.f, 0.f, 0.f, 0.f};
  f32x4 acc[6][2][2];
#pragma unroll
  for (int g = 0; g < 6; ++g)
#pragma unroll
    for (int r = 0; r < 2; ++r)
#pragma unroll
      for (int c = 0; c < 2; ++c) acc[g][r][c] = zero4;

#pragma unroll
  for (int kc = 0; kc < 7; ++kc) {
    bf16x8 ax0 = afrag(pX0, kc * 32);
    bf16x8 ax1 = afrag(pX1, kc * 32);
    bf16x8 ah0 = afrag(pH0, kc * 32);
    bf16x8 ah1 = afrag(pH1, kc * 32);
#pragma unroll
    for (int g = 0; g < 3; ++g) {
      bf16x8 bi0 = *(const bf16x8*)(pBi[g][0] + kc * 512);
      bf16x8 bi1 = *(const bf16x8*)(pBi[g][1] + kc * 512);
      bf16x8 bh0 = *(const bf16x8*)(pBh[g][0] + kc * 512);
      bf16x8 bh1 = *(const bf16x8*)(pBh[g][1] + kc * 512);
      acc[g][0][0] = __builtin_amdgcn_mfma_f32_16x16x32_bf16(ax0, bi0, acc[g][0][0], 0, 0, 0);
      acc[g][0][1] = __builtin_amdgcn_mfma_f32_16x16x32_bf16(ax0, bi1, acc[g][0][1], 0, 0, 0);
      acc[g][1][0] = __builtin_amdgcn_mfma_f32_16x16x32_bf16(ax1, bi0, acc[g][1][0], 0, 0, 0);
      acc[g][1][1] = __builtin_amdgcn_mfma_f32_16x16x32_bf16(ax1, bi1, acc[g][1][1], 0, 0, 0);
      acc[g + 3][0][0] = __builtin_amdgcn_mfma_f32_16x16x32_bf16(ah0, bh0, acc[g + 3][0][0], 0, 0, 0);
      acc[g + 3][0][1] = __builtin_amdgcn_mfma_f32_16x16x32_bf16(ah0, bh1, acc[g + 3][0][1], 0, 0, 0);
      acc[g + 3][1][0] = __builtin_amdgcn_mfma_f32_16x16x32_bf16(ah1, bh0, acc[g + 3][1][0], 0, 0, 0);
      acc[g + 3][1][1] = __builtin_amdgcn_mfma_f32_16x16x32_bf16(ah1, bh1, acc[g + 3][1][1], 0, 0, 0);
    }
  }
#pragma unroll
  for (int r = 0; r < 2; ++r) {
#pragma unroll
    for (int c = 0; c < 2; ++c) {
      int col = col0 + c * 16 + l15;
      if (col >= GG) continue;
      float br = bih[col],       bhr = bhh[col];
      float bz = bih[200 + col], bhz = bhh[200 + col];
      float bn = bih[400 + col], bhn = bhh[400 + col];
#pragma unroll
      for (int i = 0; i < 4; ++i) {
        int row = row0 + w * 32 + r * 16 + quad * 4 + i;
        if (row >= R) continue;
        float rr = sigm_fast(acc[0][r][c][i] + br + acc[3][r][c][i] + bhr);
        float zz = sigm_fast(acc[1][r][c][i] + bz + acc[4][r][c][i] + bhz);
        float nn = tanh_fast(acc[2][r][c][i] + bn + rr * (acc[5][r][c][i] + bhn));
        float hval = ldv<TI>(H + (size_t)row * GG + col);
        float o = (1.f - zz) * nn + zz * hval;
        if (relu_out) o = fmaxf(o, 0.f);
        if constexpr (sizeof(TO) == 2) Out[(size_t)row * GG + col] = f2bf(o);
        else Out[(size_t)row * GG + col] = o;
      }
    }
  }
}

// ---------------- fp32 tiled GEMM (small readout shapes) ----------------
#define Bb 64
#define Bn 64
#define Bk 16
__global__ __launch_bounds__(256) void gemm_kernel(
    const float* __restrict__ A, const float* __restrict__ W,
    const float* __restrict__ bias, const float* __restrict__ rowmask,
    float* __restrict__ Cf, void* __restrict__ Oout, const int* __restrict__ oflag,
    int Mr, int Nc, int K, int act)
{
  __shared__ float As[Bk][Bb + 1];
  __shared__ float Ws[Bk][Bn];
  int row0 = blockIdx.x * Bb, col0 = blockIdx.y * Bn;
  int tid = threadIdx.x;
  int ty = tid >> 4, tx = tid & 15;
  float acc[4][4] = {};
  for (int k0 = 0; k0 < K; k0 += Bk) {
    for (int l = tid; l < Bb * Bk; l += 256) {
      int m = l >> 4, kk = l & 15;
      int r = row0 + m, k = k0 + kk;
      As[kk][m] = (r < Mr && k < K) ? A[(size_t)r * K + k] : 0.f;
    }
    for (int l = tid; l < Bk * Bn; l += 256) {
      int kk = l >> 6, nn = l & 63;
      int k = k0 + kk, c = col0 + nn;
      Ws[kk][nn] = (k < K && c < Nc) ? W[(size_t)k * Nc + c] : 0.f;
    }
    __syncthreads();
#pragma unroll
    for (int kk = 0; kk < Bk; ++kk) {
      float av[4], bv[4];
#pragma unroll
      for (int i = 0; i < 4; ++i) av[i] = As[kk][ty * 4 + i];
#pragma unroll
      for (int j = 0; j < 4; ++j) bv[j] = Ws[kk][tx * 4 + j];
#pragma unroll
      for (int i = 0; i < 4; ++i)
#pragma unroll
        for (int j = 0; j < 4; ++j) acc[i][j] += av[i] * bv[j];
    }
    __syncthreads();
  }
  int isbf = (oflag != nullptr) ? *oflag : 0;
#pragma unroll
  for (int i = 0; i < 4; ++i) {
    int r = row0 + ty * 4 + i;
    if (r >= Mr) continue;
    bool valid = (rowmask == nullptr) || (rowmask[r] > 0.f);
#pragma unroll
    for (int j = 0; j < 4; ++j) {
      int c = col0 + tx * 4 + j;
      if (c >= Nc) continue;
      float v = valid ? (acc[i][j] + (bias ? bias[c] : 0.f)) : 0.f;
      if (act == 1) v = leakyf(v);
      else if (act == 2) v = elu_fast(v);
      else if (act == 3) v = fmaxf(v, 0.f);
      size_t idx = (size_t)r * Nc + c;
      if (Oout) {
        if (isbf) ((__hip_bfloat16*)Oout)[idx] = __float2bfloat16(v);
        else      ((float*)Oout)[idx] = v;
      } else {
        Cf[idx] = v;
      }
    }
  }
}

// ---------------- per-node dot(s), bf16 input ----------------
__global__ __launch_bounds__(256) void node_dot2(
    const unsigned short* __restrict__ X, const float* __restrict__ w1,
    const float* __restrict__ w2,
    float* __restrict__ o1, float* __restrict__ o2, int N)
{
  int v = (blockIdx.x * 256 + threadIdx.x) >> 6;
  int lane = threadIdx.x & 63;
  if (v >= N) return;
  float d1 = 0.f, d2 = 0.f;
  for (int k = lane; k < GG; k += 64) {
    float x = bf2f(X[(size_t)v * GG + k]);
    d1 += x * w1[k];
    if (w2) d2 += x * w2[k];
  }
  for (int off = 32; off; off >>= 1) {
    d1 += __shfl_down(d1, off);
    if (w2) d2 += __shfl_down(d2, off);
  }
  if (lane == 0) { o1[v] = d1; if (w2) o2[v] = d2; }
}

__global__ __launch_bounds__(256) void graph_sum(
    const unsigned short* __restrict__ h, float* __restrict__ g)
{
  int b = blockIdx.x, k = threadIdx.x;
  if (k < GG) {
    float a = 0.f;
    for (int i = 0; i < 50; ++i) a += bf2f(h[((size_t)b * 50 + i) * GG + k]);
    g[(size_t)b * GG + k] = a;
  }
}

__global__ __launch_bounds__(256) void attn_kernel(
    const float* __restrict__ g, const unsigned short* __restrict__ h2,
    const float* __restrict__ w1, const float* __restrict__ dh,
    const float* __restrict__ rb, float* __restrict__ weighted)
{
  int b = blockIdx.x;
  __shared__ float red[256];
  __shared__ float zs[50];
  __shared__ float as_[50];
  __shared__ float dgs;
  int tid = threadIdx.x;
  float p = 0.f;
  if (tid < GG) p = fmaxf(g[(size_t)b * GG + tid], 0.f) * w1[tid];
  red[tid] = p;
  __syncthreads();
  for (int s = 128; s; s >>= 1) { if (tid < s) red[tid] += red[tid + s]; __syncthreads(); }
  if (tid == 0) dgs = red[0];
  __syncthreads();
  if (tid < 50) zs[tid] = leakyf(dgs + dh[b * 50 + tid] + rb[0]);
  __syncthreads();
  if (tid == 0) {
    float m = -1e30f;
    for (int i = 0; i < 50; ++i) m = fmaxf(m, zs[i]);
    float s = 0.f;
    for (int i = 0; i < 50; ++i) { float e = __expf(zs[i] - m); as_[i] = e; s += e; }
    float inv = 1.f / s;
    for (int i = 0; i < 50; ++i) as_[i] *= inv;
  }
  __syncthreads();
  if (tid < GG) {
    float a = 0.f;
    for (int i = 0; i < 50; ++i) a += as_[i] * bf2f(h2[((size_t)b * 50 + i) * GG + tid]);
    weighted[(size_t)b * GG + tid] = a;
  }
}

// ---------------- host ----------------
static inline int gemm_grid(int Mr, int Nc) {
  int nrow = (Mr + 127) / 128, ncol = (Nc + 63) / 64;
  return ((nrow + 7) / 8) * 8 * ncol;
}
static inline int gru_grid(int R) {
  int nrow = (R + 127) / 128;
  return ((nrow + 7) / 8) * 56;
}

extern "C" void kernel_launch(void* const* d_in, const int* in_sizes, int n_in,
                              void* d_out, int out_size, void* d_ws, size_t ws_size,
                              hipStream_t stream)
{
  (void)n_in; (void)out_size; (void)ws_size;
  const int N = NN, M = MM, B = BB, F = FF, G = GG, P = PP;
  const int PK7 = 14 * 7 * 512, PK2 = 14 * 2 * 512;
  float* ws = (float*)d_ws;
  size_t off = 0;
  auto alloc = [&](size_t n) { size_t o = off; off += (n + 63) & ~(size_t)63; return o; };

  size_t o_flag = alloc(16);
  size_t o_pn_w = alloc(F * G), o_pn_b = alloc(G);
  size_t o_pe1_w = alloc((F + EE) * G), o_pe1_b = alloc(G);
  size_t o_pe2_w = alloc(2 * G), o_pe2_b = alloc(1);
  size_t o_et_w = alloc(G * G), o_et_b = alloc(G);
  size_t o_g0_wih = alloc(G * 3 * G), o_g0_whh = alloc(G * 3 * G);
  size_t o_g0_bih = alloc(3 * G), o_g0_bhh = alloc(3 * G);
  size_t o_lpe_w = alloc(2 * G), o_lpe_b = alloc(1);
  size_t o_lpn_w = alloc(G * G), o_lpn_b = alloc(G);
  size_t o_g1_wih = alloc(G * 3 * G), o_g1_whh = alloc(G * 3 * G);
  size_t o_g1_bih = alloc(3 * G), o_g1_bhh = alloc(3 * G);
  size_t o_rl_w = alloc(2 * 2 * G), o_rl_b = alloc(2);
  size_t o_rp_w = alloc(2 * G * G), o_rp_b = alloc(2 * G);
  size_t o_rg_wih = alloc(2 * G * 3 * G), o_rg_whh = alloc(2 * G * 3 * G);
  size_t o_rg_bih = alloc(2 * 3 * G), o_rg_bhh = alloc(2 * 3 * G);
  size_t o_t_w = alloc(G * P), o_t_b = alloc(P);
  size_t o_Xnb = alloc((size_t)N * 40 / 2 + 64);
  size_t o_Xe = alloc((size_t)M * EE);
  size_t o_B1 = alloc((size_t)N * G);
  size_t o_B2 = alloc((size_t)N * G);
  size_t o_B3 = alloc((size_t)N * G);
  size_t o_ssum = alloc(N);
  size_t o_gd = alloc(N), o_gs = alloc(N);
  size_t o_dh0 = alloc(N), o_dh1 = alloc(N);
  size_t o_gv0 = alloc((size_t)B * G), o_gwt = alloc((size_t)B * G), o_grep = alloc((size_t)B * G + 64);
  size_t o_gv1 = alloc((size_t)B * G + 64), o_gv2 = alloc((size_t)B * G + 64);
  size_t o_etP  = alloc(PK7 / 2 + 64), o_lpnP = alloc(PK7 / 2 + 64);
  size_t o_g0ihP = alloc(3 * PK7 / 2 + 64), o_g0hhP = alloc(3 * PK7 / 2 + 64);
  size_t o_g1ihP = alloc(3 * PK7 / 2 + 64), o_g1hhP = alloc(3 * PK7 / 2 + 64);
  size_t o_rg0ihP = alloc(3 * PK7 / 2 + 64), o_rg0hhP = alloc(3 * PK7 / 2 + 64);
  size_t o_rg1ihP = alloc(3 * PK7 / 2 + 64), o_rg1hhP = alloc(3 * PK7 / 2 + 64);
  size_t o_pnP = alloc(PK2 / 2 + 64), o_pe1P = alloc(PK2 / 2 + 64);
  size_t o_cnt = alloc(N), o_off = alloc(N), o_cur = alloc(N);
  size_t o_elist = alloc(M), o_bsum = alloc(64), o_incl = alloc(N);

  int* flag = (int*)(ws + o_flag);
  int* cntA = (int*)(ws + o_cnt);
  int* offA = (int*)(ws + o_off);
  int* curA = (int*)(ws + o_cur);
  int* elist = (int*)(ws + o_elist);
  int* bsum = (int*)(ws + o_bsum);
  int* incl = (int*)(ws + o_incl);
  unsigned short* Xnb = (unsigned short*)(ws + o_Xnb);
  unsigned short* B1b = (unsigned short*)(ws + o_B1);
  unsigned short* B2b = (unsigned short*)(ws + o_B2);
  unsigned short* B3b = (unsigned short*)(ws + o_B3);

  CvtJobs32 jobs;
  int ji = 0;
  auto push = [&](int idx, size_t dsto) {
    jobs.j[ji].s = d_in[idx];
    jobs.j[ji].d = ws + dsto;
    jobs.j[ji].n = in_sizes[idx];
    jobs.j[ji].pad = 0;
    ++ji;
  };
  push(1, o_Xe);
  push(2, o_pn_w);  push(3, o_pn_b);
  push(4, o_pe1_w); push(5, o_pe1_b);
  push(6, o_pe2_w); push(7, o_pe2_b);
  push(8, o_et_w);  push(9, o_et_b);
  push(10, o_g0_wih); push(11, o_g0_whh); push(12, o_g0_bih); push(13, o_g0_bhh);
  push(14, o_lpe_w);  push(15, o_lpe_b);
  push(16, o_lpn_w);  push(17, o_lpn_b);
  push(18, o_g1_wih); push(19, o_g1_whh); push(20, o_g1_bih); push(21, o_g1_bhh);
  push(22, o_rl_w);   push(23, o_rl_b);
  push(24, o_rp_w);   push(25, o_rp_b);
  push(26, o_rg_wih); push(27, o_rg_whh); push(28, o_rg_bih); push(29, o_rg_bhh);
  push(30, o_t_w);    push(31, o_t_b);

  const int* src = (const int*)d_in[32];
  const int* dst = (const int*)d_in[33];

  dim3 blk(256);
  detect_dtype<<<dim3(1), blk, 0, stream>>>((const unsigned int*)d_in[0], flag);
  cvt_any<<<dim3(512, 31), blk, 0, stream>>>(jobs, flag);
  cvt_xn<<<dim3((N * 40 + 255) / 256), blk, 0, stream>>>(d_in[0], Xnb, flag, N);

  // ---- CSR build (by dst) ----
  hipMemsetAsync(cntA, 0, (size_t)N * 4, stream);
  hist_kernel<<<dim3((M + 255) / 256), blk, 0, stream>>>(dst, cntA, M);
  int nscb = (N + SCHUNK - 1) / SCHUNK;
  scan1_kernel<<<dim3(nscb), blk, 0, stream>>>(cntA, incl, bsum, N);
  scan2_kernel<<<dim3(1), dim3(64), 0, stream>>>(bsum, nscb);
  scan3_kernel<<<dim3((N + 255) / 256), blk, 0, stream>>>(incl, cntA, bsum, offA, curA, N);
  fill_kernel<<<dim3((M + 255) / 256), blk, 0, stream>>>(dst, curA, elist, M);

  // ---- weight packing (fragment-major) ----
  PJobs28 pj;
  int pi = 0;
  auto ppush = [&](size_t srcO, size_t dstOshorts_base, int slot_shorts, int K, int Ns, int coff, int nkc) {
    pj.j[pi].s = ws + srcO;
    pj.j[pi].d = (unsigned short*)(ws + dstOshorts_base) + slot_shorts;
    pj.j[pi].K = K; pj.j[pi].Ns = Ns; pj.j[pi].coff = coff; pj.j[pi].nkc = nkc;
    ++pi;
  };
  ppush(o_et_w,  o_etP,  0, G, G, 0, 7);
  ppush(o_lpn_w, o_lpnP, 0, G, G, 0, 7);
  for (int g = 0; g < 3; ++g) {
    ppush(o_g0_wih, o_g0ihP, g * PK7, G, 3 * G, g * G, 7);
    ppush(o_g0_whh, o_g0hhP, g * PK7, G, 3 * G, g * G, 7);
    ppush(o_g1_wih, o_g1ihP, g * PK7, G, 3 * G, g * G, 7);
    ppush(o_g1_whh, o_g1hhP, g * PK7, G, 3 * G, g * G, 7);
    ppush(o_rg_wih, o_rg0ihP, g * PK7, G, 3 * G, g * G, 7);
    ppush(o_rg_whh, o_rg0hhP, g * PK7, G, 3 * G, g * G, 7);
    ppush(o_rg_wih + (size_t)G * 3 * G, o_rg1ihP, g * PK7, G, 3 * G, g * G, 7);
    ppush(o_rg_whh + (size_t)G * 3 * G, o_rg1hhP, g * PK7, G, 3 * G, g * G, 7);
  }
  ppush(o_pn_w,  o_pnP,  0, F, G, 0, 2);
  ppush(o_pe1_w, o_pe1P, 0, F, G, 0, 2);
  pack_bf16<<<dim3(64, 28), blk, 0, stream>>>(pj);

  int gg = gemm_grid(N, G);
  mfma_gemm_d<2><<<dim3(gg), blk, 0, stream>>>(
      Xnb, 40, (const unsigned short*)(ws + o_pnP),
      ws + o_pn_b, nullptr, B1b, N, G, 1);
  mfma_gemm_d<2><<<dim3(gg), blk, 0, stream>>>(
      Xnb, 40, (const unsigned short*)(ws + o_pe1P),
      nullptr, nullptr, B2b, N, G, 0);
  l1_agg<<<dim3(N), dim3(64), 0, stream>>>(ws + o_Xe, B2b, B1b,
                                           ws + o_pe1_w + (size_t)F * G, ws + o_pe1_b,
                                           ws + o_pe2_w, ws + o_pe2_w + G, ws + o_pe2_b,
                                           src, offA, cntA, elist,
                                           B3b, ws + o_ssum, N);
  mfma_gemm_d<7><<<dim3(gg), blk, 0, stream>>>(
      B3b, G, (const unsigned short*)(ws + o_etP),
      ws + o_et_b, ws + o_ssum, B2b, N, G, 2);
  mfma_gru_d<unsigned short, unsigned short><<<dim3(gru_grid(N)), blk, 0, stream>>>(
      B2b, B1b,
      (const unsigned short*)(ws + o_g0ihP), (const unsigned short*)(ws + o_g0hhP),
      ws + o_g0_bih, ws + o_g0_bhh, B3b, N, 1);

  // ---- layer 2 ----
  dim3 gWave((N + 3) / 4);
  node_dot2<<<gWave, blk, 0, stream>>>(B3b, ws + o_lpe_w, ws + o_lpe_w + G,
                                       ws + o_gd, ws + o_gs, N);
  mfma_gemm_d<7><<<dim3(gg), blk, 0, stream>>>(
      B3b, G, (const unsigned short*)(ws + o_lpnP),
      ws + o_lpn_b, nullptr, B1b, N, G, 0);
  l2_agg<<<dim3(N), dim3(64), 0, stream>>>(B1b, ws + o_gd, ws + o_gs, ws + o_lpe_b,
                                           src, offA, cntA, elist, B2b, N);
  mfma_gru_d<unsigned short, unsigned short><<<dim3(gru_grid(N)), blk, 0, stream>>>(
      B2b, B3b,
      (const unsigned short*)(ws + o_g1ihP), (const unsigned short*)(ws + o_g1hhP),
      ws + o_g1_bih, ws + o_g1_bhh, B1b, N, 1);

  // ---- readout ----
  graph_sum<<<dim3(B), blk, 0, stream>>>(B1b, ws + o_gv0);
  // dh for both timesteps in one pass (h2 = B1b is fixed)
  node_dot2<<<gWave, blk, 0, stream>>>(B1b, ws + o_rl_w + G, ws + o_rl_w + 2 * G + G,
                                       ws + o_dh0, ws + o_dh1, N);
  dim3 gBG((B + Bb - 1) / Bb, (G + Bn - 1) / Bn);
  size_t gcur = o_gv0, gnext = o_gv1;
  for (int t = 0; t < 2; ++t) {
    attn_kernel<<<dim3(B), blk, 0, stream>>>(ws + gcur, B1b, ws + o_rl_w + t * 2 * G,
                                             ws + (t == 0 ? o_dh0 : o_dh1),
                                             ws + o_rl_b + t, ws + o_gwt);
    gemm_kernel<<<gBG, blk, 0, stream>>>(ws + o_gwt, ws + o_rp_w + (size_t)t * G * G,
                                         ws + o_rp_b + t * G, nullptr,
                                         ws + o_grep, nullptr, nullptr, B, G, G, 2);
    mfma_gru_d<float, float><<<dim3(gru_grid(B)), blk, 0, stream>>>(
        ws + o_grep, ws + gcur,
        (const unsigned short*)(ws + (t == 0 ? o_rg0ihP : o_rg1ihP)),
        (const unsigned short*)(ws + (t == 0 ? o_rg0hhP : o_rg1hhP)),
        ws + o_rg_bih + t * 3 * G, ws + o_rg_bhh + t * 3 * G,
        ws + gnext, B, 0);
    gcur = gnext;
    gnext = o_gv2;
  }
  dim3 gOut((B + Bb - 1) / Bb, (P + Bn - 1) / Bn);
  gemm_kernel<<<gOut, blk, 0, stream>>>(ws + gcur, ws + o_t_w, ws + o_t_b, nullptr,
                                        nullptr, d_out, flag, B, P, G, 0);
}